// Round 2
// baseline (295.210 us; speedup 1.0000x reference)
//
#include <hip/hip_runtime.h>
#include <hip/hip_bf16.h>
#include <hip/hip_cooperative_groups.h>

namespace cg = cooperative_groups;

// Problem constants
constexpr int N = 4096, E = 131072, OUTF = 86, NB = 16, HEADS = 4, DH = 16;
constexpr int CAP = 128;   // padded bucket capacity per node (mean deg = 32)
constexpr int NSPLIT = 4, KEYS = N / NSPLIT;  // 1024 keys per attention split
constexpr int PCKS = 8;    // u64 stride per node in pck (64 B line per node)

typedef __attribute__((ext_vector_type(8))) short short8;
typedef __attribute__((ext_vector_type(4))) float f32x4;

constexpr unsigned long long PK_MASK = (1ULL << 40) - 1;  // low 40: fixed-point deg
constexpr float PK_SCALE = 1.0f / 16777216.0f;            // 2^-24

// Workspace offsets (float units, 16B-aligned)
constexpr size_t OFF_PCK   = 0;                           // N*PCKS u64 = 16N words
constexpr size_t OFF_INV   = OFF_PCK + 16 * (size_t)N;    // 16
constexpr size_t OFF_BUFA  = OFF_INV + 16;                // N*64 (xW1)
constexpr size_t OFF_QP    = OFF_BUFA + (size_t)N * 64;   // HEADS*N*16 bf16 = N*32 floats
constexpr size_t OFF_KP    = OFF_QP + (size_t)N * 32;
constexpr size_t OFF_VP    = OFF_KP + (size_t)N * 32;     // [h][16][N] bf16
constexpr size_t OFF_H2    = OFF_VP + (size_t)N * 32;     // N*86 (h2pre)
constexpr size_t OFF_EPAIR = OFF_H2 + (size_t)N * 86;     // N*CAP int2 {src, w}
constexpr size_t OFF_NORMV = OFF_EPAIR + (size_t)2 * N * CAP;  // N*CAP floats
constexpr size_t OFF_OPART = OFF_NORMV + (size_t)N * CAP; // HEADS*N*NSPLIT*16
constexpr size_t OFF_LPART = OFF_OPART + (size_t)HEADS * N * NSPLIT * 16;  // HEADS*N*NSPLIT

__device__ inline unsigned short f2bf(float f) {  // RNE float->bf16
    unsigned u = __builtin_bit_cast(unsigned, f);
    u += 0x7FFFu + ((u >> 16) & 1u);
    return (unsigned short)(u >> 16);
}

__device__ inline unsigned pk2bf(float a, float b) {  // packed RNE pair
    __hip_bfloat162 h2 = __float22bfloat162_rn(make_float2(a, b));
    union { __hip_bfloat162 h; unsigned u; } c;
    c.h = h2;
    return c.u;
}

__device__ inline float pk_deg(unsigned long long pk) {   // decode weighted degree
    return (float)(pk & PK_MASK) * PK_SCALE;
}

// ================= single fused cooperative kernel =================
// 256 blocks x 1024 threads (16 waves) = 4096 waves, 1 block/CU, all co-resident.
// Stage mapping (every stage needs exactly 4096 waves):
//   S0: edge bucket fill (waves 0-7) || gemm1 x@W1^T (waves 8-15) || out-init (block 0)
//   S1: agg1 + QKV pack (1 node/wave)
//   S2: MFMA flash attention (wave = (qtile, head, split))
//   S3: combine + Wout + W2 gemms (block = 16 rows)
//   S4: agg2 + per-graph reduce + atomics
// LDS: single 55552-byte arena re-purposed per stage (max user = S1's 55552).
__global__ __launch_bounds__(1024) void fused_kernel(
        const float* __restrict__ x, const int* __restrict__ ei,
        const float* __restrict__ ea, const int* __restrict__ batch,
        const float* __restrict__ W1, const float* __restrict__ b1,
        const float* __restrict__ Win, const float* __restrict__ b_in,
        const float* __restrict__ Wout, const float* __restrict__ b_out,
        const float* __restrict__ W2, const float* __restrict__ b2,
        float* __restrict__ ws, float* __restrict__ out) {
    __shared__ __align__(16) char smem[55552];

    cg::grid_group grid = cg::this_grid();

    const int tid = threadIdx.x, lane = tid & 63, wv = tid >> 6;
    const int gw = blockIdx.x * 16 + wv;          // global wave id [0, 4096)

    unsigned long long* pck = (unsigned long long*)(ws + OFF_PCK);
    int2*  epair = (int2*)(ws + OFF_EPAIR);
    float* bufA  = ws + OFF_BUFA;
    float* invcnt = ws + OFF_INV;

    // ---------------- S0: edge fill || gemm1 || out-init ----------------
    if (wv < 8) {
        // edge bucket fill: 512 thr/block * 256 blocks = 131072 = E
        int e = blockIdx.x * 512 + tid;
        int s = ei[e], d = ei[E + e];
        float w = ea[e];
        unsigned long long a = (1ULL << 40) + (unsigned long long)(unsigned)(w * 16777216.0f + 0.5f);
        unsigned long long o = atomicAdd(&pck[(size_t)d * PCKS], a);
        int p = (int)(o >> 40);
        if (p < CAP) epair[(size_t)d * CAP + p] = make_int2(s, __float_as_int(w));
    } else {
        // gemm1: 2048 waves * 2 rows = 4096 rows. Lane = output col.
        int gw2 = blockIdx.x * 8 + (wv - 8);
        int r0 = gw2 * 2, r1 = r0 + 1;
        float4 xa = ((const float4*)x)[(size_t)r0 * 16 + (lane & 15)];
        float4 xb = ((const float4*)x)[(size_t)r1 * 16 + (lane & 15)];
        float acc0 = 0.f, acc1 = 0.f;
#pragma unroll
        for (int k4 = 0; k4 < 16; ++k4) {
            float4 w4 = ((const float4*)W1)[lane * 16 + k4];  // W1[lane][4k4..] (L1-resident)
            float ax = __shfl(xa.x, k4), ay = __shfl(xa.y, k4);
            float az = __shfl(xa.z, k4), aw = __shfl(xa.w, k4);
            acc0 += ax * w4.x + ay * w4.y + az * w4.z + aw * w4.w;
            float bx = __shfl(xb.x, k4), by = __shfl(xb.y, k4);
            float bz = __shfl(xb.z, k4), bw = __shfl(xb.w, k4);
            acc1 += bx * w4.x + by * w4.y + bz * w4.z + bw * w4.w;
        }
        bufA[(size_t)r0 * 64 + lane] = acc0;
        bufA[(size_t)r1 * 64 + lane] = acc1;
    }
    if (blockIdx.x == 0) {
        // out-init: parallel binary searches for graph boundaries, then broadcast
        int* bnd = (int*)smem;
        __syncthreads();
        if (tid <= NB) {
            int b = tid, lo = 0, hi = N;
            while (lo < hi) { int m = (lo + hi) >> 1; if (batch[m] < b) lo = m + 1; else hi = m; }
            bnd[tid] = lo;
        }
        __syncthreads();
        if (tid < NB) {
            int cnt = bnd[tid + 1] - bnd[tid];
            invcnt[tid] = cnt > 0 ? 1.0f / (float)cnt : 0.0f;
        }
        for (int idx = tid; idx < NB * OUTF; idx += 1024) {
            int b = idx / OUTF;
            int cnt = bnd[b + 1] - bnd[b];
            out[idx] = cnt > 0 ? b2[idx - b * OUTF] : 0.0f;
        }
    }
    grid.sync();

    // ---------------- S1: agg1(+b1,ReLU) -> QKV gemm + bf16 pack ----------------
    {
        float4* Ws4 = (float4*)smem;               // [k4][c] pad 200: 51200 B
        float*  Af  = (float*)(smem + 51200);      // 16*68 floats: 4352 B
        float*       normv = ws + OFF_NORMV;
        unsigned short* Qp = (unsigned short*)(ws + OFF_QP);
        unsigned short* Kp = (unsigned short*)(ws + OFF_KP);
        unsigned short* Vp = (unsigned short*)(ws + OFF_VP);

        for (int idx = tid; idx < 192 * 16; idx += 1024) {
            int c = idx >> 4, k4 = idx & 15;
            Ws4[k4 * 200 + c] = ((const float4*)Win)[idx];
        }

        const int node = gw;
        {
            const unsigned long long pkn = pck[(size_t)node * PCKS];
            const float di = rsqrtf(pk_deg(pkn) + 1.0f);   // self-loop: deg+1
            float acc0 = (di * di) * bufA[(size_t)node * 64 + lane];
            float acc1 = 0.f, acc2 = 0.f, acc3 = 0.f;
            const int cnt = min((int)(pkn >> 40), CAP);
            const int2* pe = epair + (size_t)node * CAP;
            for (int base = 0; base < cnt; base += 64) {
                int rem = cnt - base;
                int   sl = 0;
                float nl = 0.f;
                if (lane < rem) {
                    int2 e = pe[base + lane];
                    sl = e.x;
                    float w = __int_as_float(e.y);
                    nl = rsqrtf(pk_deg(pck[(size_t)sl * PCKS]) + 1.0f) * w * di;
                    normv[(size_t)node * CAP + base + lane] = nl;   // for S4
                }
                int m = rem < 64 ? rem : 64;
                int j = 0;
                for (; j + 8 <= m; j += 8) {
                    int   s0 = __shfl(sl, j),     s1 = __shfl(sl, j + 1);
                    int   s2 = __shfl(sl, j + 2), s3 = __shfl(sl, j + 3);
                    int   s4 = __shfl(sl, j + 4), s5 = __shfl(sl, j + 5);
                    int   s6 = __shfl(sl, j + 6), s7 = __shfl(sl, j + 7);
                    float n0 = __shfl(nl, j),     n1 = __shfl(nl, j + 1);
                    float n2 = __shfl(nl, j + 2), n3 = __shfl(nl, j + 3);
                    float n4 = __shfl(nl, j + 4), n5 = __shfl(nl, j + 5);
                    float n6 = __shfl(nl, j + 6), n7 = __shfl(nl, j + 7);
                    float v0 = bufA[(size_t)s0 * 64 + lane], v1 = bufA[(size_t)s1 * 64 + lane];
                    float v2 = bufA[(size_t)s2 * 64 + lane], v3 = bufA[(size_t)s3 * 64 + lane];
                    float v4 = bufA[(size_t)s4 * 64 + lane], v5 = bufA[(size_t)s5 * 64 + lane];
                    float v6 = bufA[(size_t)s6 * 64 + lane], v7 = bufA[(size_t)s7 * 64 + lane];
                    acc0 += n0 * v0; acc1 += n1 * v1; acc2 += n2 * v2; acc3 += n3 * v3;
                    acc0 += n4 * v4; acc1 += n5 * v5; acc2 += n6 * v6; acc3 += n7 * v7;
                }
                for (; j + 4 <= m; j += 4) {
                    int   s0 = __shfl(sl, j),     s1 = __shfl(sl, j + 1);
                    int   s2 = __shfl(sl, j + 2), s3 = __shfl(sl, j + 3);
                    float n0 = __shfl(nl, j),     n1 = __shfl(nl, j + 1);
                    float n2 = __shfl(nl, j + 2), n3 = __shfl(nl, j + 3);
                    acc0 += n0 * bufA[(size_t)s0 * 64 + lane];
                    acc1 += n1 * bufA[(size_t)s1 * 64 + lane];
                    acc2 += n2 * bufA[(size_t)s2 * 64 + lane];
                    acc3 += n3 * bufA[(size_t)s3 * 64 + lane];
                }
                for (; j < m; ++j) {
                    int   s0 = __shfl(sl, j);
                    float n0 = __shfl(nl, j);
                    acc0 += n0 * bufA[(size_t)s0 * 64 + lane];
                }
            }
            Af[wv * 68 + lane] = fmaxf((acc0 + acc1) + (acc2 + acc3) + b1[lane], 0.0f);
        }
        __syncthreads();

        // QKV: wave wv computes row (node); lane handles cols {lane, lane+64, lane+128}
        {
            const float4* Af4 = (const float4*)Af;
            float acc[3];
#pragma unroll
            for (int i = 0; i < 3; ++i) acc[i] = b_in[lane + 64 * i];
#pragma unroll
            for (int k4 = 0; k4 < 16; ++k4) {
                float4 a = Af4[wv * 17 + k4];          // wave-broadcast
#pragma unroll
                for (int i = 0; i < 3; ++i) {
                    float4 w = Ws4[k4 * 200 + lane + 64 * i];  // lane-consecutive
                    acc[i] += a.x * w.x + a.y * w.y + a.z * w.z + a.w * w.w;
                }
            }
            const int row = node;
#pragma unroll
            for (int i = 0; i < 3; ++i) {
                int c = lane + 64 * i;
                float v = acc[i];
                if (c < 64) {
                    int h = c >> 4, d = c & 15;
                    Qp[((size_t)h * N + row) * 16 + d] = f2bf(v * 0.25f);  // 1/sqrt(DH)
                } else if (c < 128) {
                    int c2 = c - 64, h = c2 >> 4, d = c2 & 15;
                    Kp[((size_t)h * N + row) * 16 + d] = f2bf(v);
                } else {
                    int c2 = c - 128, h = c2 >> 4, d = c2 & 15;
                    Vp[((size_t)h * 16 + d) * N + row] = f2bf(v);
                }
            }
        }
    }
    grid.sync();

    // ---------------- S2: MFMA flash attention, KV-split ----------------
    {
        unsigned short* Plds = (unsigned short*)smem;   // 16 waves * 640 ushort = 20480 B
        const unsigned short* Qp = (const unsigned short*)(ws + OFF_QP);
        const unsigned short* Kp = (const unsigned short*)(ws + OFF_KP);
        const unsigned short* Vp = (const unsigned short*)(ws + OFF_VP);
        float* opart = ws + OFF_OPART;
        float* lpart = ws + OFF_LPART;

        const int qt = gw & 255;            // 256 q-tiles
        const int h  = (gw >> 8) & 3;       // 4 heads
        const int sp = gw >> 10;            // NSPLIT=4 splits
        const int k0 = sp * KEYS;
        const int q15 = lane & 15, quad = lane >> 4;
        const int qbase = qt * 16;

        short8 qf = {};
        if (quad < 2)
            qf = *(const short8*)&Qp[((size_t)h * N + qbase + q15) * 16 + quad * 8];

        f32x4 O = {0.f, 0.f, 0.f, 0.f};
        float l = 0.f;
        unsigned short* Pw = &Plds[wv * 640];
        const unsigned short* Kh = Kp + (size_t)h * N * 16;
        const unsigned short* Vh = Vp + ((size_t)h * 16 + q15) * N + k0;

#pragma unroll 2
        for (int ch = 0; ch < KEYS / 32; ++ch) {
#pragma unroll
            for (int t = 0; t < 2; ++t) {
                short8 kf = {};
                if (quad < 2)
                    kf = *(const short8*)&Kh[(size_t)(k0 + ch * 32 + t * 16 + q15) * 16 + quad * 8];
                f32x4 zero = {0.f, 0.f, 0.f, 0.f};
                __builtin_amdgcn_s_setprio(1);
                f32x4 s = __builtin_amdgcn_mfma_f32_16x16x32_bf16(kf, qf, zero, 0, 0, 0);
                __builtin_amdgcn_s_setprio(0);
                // C-layout: col=query=lane&15, row=key=quad*4+reg
                float p0 = __expf(s[0]), p1 = __expf(s[1]), p2 = __expf(s[2]), p3 = __expf(s[3]);
                l += (p0 + p1) + (p2 + p3);
                uint2 pk;
                pk.x = pk2bf(p0, p1);
                pk.y = pk2bf(p2, p3);
                *(uint2*)&Pw[q15 * 40 + t * 16 + quad * 4] = pk;
            }
            asm volatile("s_waitcnt lgkmcnt(0)" ::: "memory");
            short8 pf = *(const short8*)&Pw[q15 * 40 + quad * 8];   // A: m=query, k=key
            short8 vf = *(const short8*)&Vh[ch * 32 + quad * 8];    // B: n=dh,    k=key
            __builtin_amdgcn_s_setprio(1);
            O = __builtin_amdgcn_mfma_f32_16x16x32_bf16(pf, vf, O, 0, 0, 0);
            __builtin_amdgcn_s_setprio(0);
        }

        l += __shfl_xor(l, 16);
        l += __shfl_xor(l, 32);
        if (lane < 16)
            lpart[((size_t)h * N + qbase + q15) * NSPLIT + sp] = l;
#pragma unroll
        for (int r = 0; r < 4; ++r) {
            int query = qbase + quad * 4 + r;
            opart[(((size_t)h * N + query) * NSPLIT + sp) * 16 + q15] = O[r];
        }
    }
    grid.sync();

    // ---------------- S3: combine -> Wout gemm -> W2 gemm -> h2pre ----------------
    {
        float4* WoS = (float4*)smem;                       // 64*17 f4 = 17408 B
        float4* W2S = (float4*)(smem + 17408);             // 86*17 f4 = 23392 B
        float*  o_sh = (float*)(smem + 17408 + 23392);     // 16*68 = 4352 B
        float*  Bf   = (float*)(smem + 17408 + 23392 + 4352);  // 4352 B

        const float* opart = ws + OFF_OPART;
        const float* lpart = ws + OFF_LPART;
        float* h2pre = ws + OFF_H2;
        const int qbase = blockIdx.x * 16;

        if (tid < 64 * 16)
            WoS[(tid >> 4) * 17 + (tid & 15)] = ((const float4*)Wout)[tid];
        for (int idx = tid; idx < 86 * 16; idx += 1024)
            W2S[(idx >> 4) * 17 + (idx & 15)] = ((const float4*)W2)[idx];

        // combine: one (row, feat) per thread
        {
            int r = tid >> 6, f = tid & 63;
            int h = f >> 4, d = f & 15;
            size_t base = ((size_t)h * N + qbase + r) * NSPLIT;
            float L = 0.f, acc = 0.f;
#pragma unroll
            for (int s = 0; s < NSPLIT; ++s) {
                L += lpart[base + s];
                acc += opart[(base + s) * 16 + d];
            }
            o_sh[r * 68 + f] = acc / L;
        }
        __syncthreads();
        // Wout gemm: one (row, col) per thread
        float bacc;
        {
            int r = tid & 15, c = tid >> 4;
            float4* o4 = (float4*)o_sh;
            bacc = b_out[c];
#pragma unroll
            for (int k4 = 0; k4 < 16; ++k4) {
                float4 a = o4[r * 17 + k4];
                float4 w = WoS[c * 17 + k4];
                bacc += a.x * w.x + a.y * w.y + a.z * w.z + a.w * w.w;
            }
        }
        __syncthreads();   // o_sh reads done before Bf write (distinct arrays; cheap safety)
        {
            int r = tid & 15, c = tid >> 4;
            Bf[r * 68 + c] = bacc;
        }
        __syncthreads();
        // W2 gemm: 16 rows x 86 cols, threads cover (r, c) and (r, c+64)
        {
            int r = tid & 15, c0 = tid >> 4;
            float4* B4 = (float4*)Bf;
#pragma unroll
            for (int i = 0; i < 2; ++i) {
                int c = c0 + 64 * i;
                if (c < OUTF) {
                    float acc = 0.f;
#pragma unroll
                    for (int k4 = 0; k4 < 16; ++k4) {
                        float4 a = B4[r * 17 + k4];
                        float4 w = W2S[c * 17 + k4];
                        acc += a.x * w.x + a.y * w.y + a.z * w.z + a.w * w.w;
                    }
                    h2pre[(size_t)(qbase + r) * OUTF + c] = acc;
                }
            }
        }
    }
    grid.sync();

    // ---------------- S4: agg2 + per-graph pre-reduction + atomics ----------------
    {
        float (*vec)[88] = (float (*)[88])smem;        // 16*88*4 = 5632 B
        int* bix = (int*)(smem + 5632);

        const float* normv = ws + OFF_NORMV;
        const float* h2pre = ws + OFF_H2;

        const int node = gw;
        const bool hi2 = lane < (OUTF - 64);
        const int b = batch[node];
        const float inv = invcnt[b];
        const unsigned long long pkn = pck[(size_t)node * PCKS];
        const float di2 = 1.0f / (pk_deg(pkn) + 1.0f);
        const float* Hn = h2pre + (size_t)node * OUTF;
        float a0 = di2 * Hn[lane],                  a1 = 0.f, a2 = 0.f, a3 = 0.f;
        float c0 = hi2 ? di2 * Hn[64 + lane] : 0.f, c1 = 0.f, c2 = 0.f, c3 = 0.f;
        const int cnt = min((int)(pkn >> 40), CAP);
        const int2* pe = epair + (size_t)node * CAP;

        for (int base = 0; base < cnt; base += 64) {
            int rem = cnt - base;
            int   sl = 0;
            float nl = 0.f;
            if (lane < rem) {
                sl = pe[base + lane].x;
                nl = normv[(size_t)node * CAP + base + lane];
            }
            int m = rem < 64 ? rem : 64;
            int j = 0;
            for (; j + 8 <= m; j += 8) {
                int   s0 = __shfl(sl, j),     s1 = __shfl(sl, j + 1);
                int   s2 = __shfl(sl, j + 2), s3 = __shfl(sl, j + 3);
                int   s4 = __shfl(sl, j + 4), s5 = __shfl(sl, j + 5);
                int   s6 = __shfl(sl, j + 6), s7 = __shfl(sl, j + 7);
                float n0 = __shfl(nl, j),     n1 = __shfl(nl, j + 1);
                float n2 = __shfl(nl, j + 2), n3 = __shfl(nl, j + 3);
                float n4 = __shfl(nl, j + 4), n5 = __shfl(nl, j + 5);
                float n6 = __shfl(nl, j + 6), n7 = __shfl(nl, j + 7);
                const float* H0 = h2pre + (size_t)s0 * OUTF;
                const float* H1 = h2pre + (size_t)s1 * OUTF;
                const float* H2 = h2pre + (size_t)s2 * OUTF;
                const float* H3 = h2pre + (size_t)s3 * OUTF;
                const float* H4 = h2pre + (size_t)s4 * OUTF;
                const float* H5 = h2pre + (size_t)s5 * OUTF;
                const float* H6 = h2pre + (size_t)s6 * OUTF;
                const float* H7 = h2pre + (size_t)s7 * OUTF;
                float v0 = H0[lane], v1 = H1[lane], v2 = H2[lane], v3 = H3[lane];
                float v4 = H4[lane], v5 = H5[lane], v6 = H6[lane], v7 = H7[lane];
                a0 += n0 * v0; a1 += n1 * v1; a2 += n2 * v2; a3 += n3 * v3;
                a0 += n4 * v4; a1 += n5 * v5; a2 += n6 * v6; a3 += n7 * v7;
                if (hi2) {
                    float w0 = H0[64 + lane], w1 = H1[64 + lane];
                    float w2 = H2[64 + lane], w3 = H3[64 + lane];
                    float w4 = H4[64 + lane], w5 = H5[64 + lane];
                    float w6 = H6[64 + lane], w7 = H7[64 + lane];
                    c0 += n0 * w0; c1 += n1 * w1; c2 += n2 * w2; c3 += n3 * w3;
                    c0 += n4 * w4; c1 += n5 * w5; c2 += n6 * w6; c3 += n7 * w7;
                }
            }
            for (; j + 4 <= m; j += 4) {
                int   s0 = __shfl(sl, j),     s1 = __shfl(sl, j + 1);
                int   s2 = __shfl(sl, j + 2), s3 = __shfl(sl, j + 3);
                float n0 = __shfl(nl, j),     n1 = __shfl(nl, j + 1);
                float n2 = __shfl(nl, j + 2), n3 = __shfl(nl, j + 3);
                const float* H0 = h2pre + (size_t)s0 * OUTF;
                const float* H1 = h2pre + (size_t)s1 * OUTF;
                const float* H2 = h2pre + (size_t)s2 * OUTF;
                const float* H3 = h2pre + (size_t)s3 * OUTF;
                a0 += n0 * H0[lane]; if (hi2) c0 += n0 * H0[64 + lane];
                a1 += n1 * H1[lane]; if (hi2) c1 += n1 * H1[64 + lane];
                a2 += n2 * H2[lane]; if (hi2) c2 += n2 * H2[64 + lane];
                a3 += n3 * H3[lane]; if (hi2) c3 += n3 * H3[64 + lane];
            }
            for (; j < m; ++j) {
                int   s0 = __shfl(sl, j);
                float n0 = __shfl(nl, j);
                const float* H0 = h2pre + (size_t)s0 * OUTF;
                a0 += n0 * H0[lane];
                if (hi2) c0 += n0 * H0[64 + lane];
            }
        }
        vec[wv][lane] = ((a0 + a1) + (a2 + a3)) * inv;
        if (hi2) vec[wv][64 + lane] = ((c0 + c1) + (c2 + c3)) * inv;
        if (lane == 0) bix[wv] = b;
        __syncthreads();
        // per-graph pre-reduction over the 16 sorted nodes: 1 atomic per (graph, feat)
        if (tid < OUTF) {
            int curb = bix[0];
            float acc = 0.f;
#pragma unroll
            for (int w = 0; w < 16; ++w) {
                int bw = bix[w];
                if (bw != curb) {
                    atomicAdd(&out[curb * OUTF + tid], acc);
                    curb = bw; acc = 0.f;
                }
                acc += vec[w][tid];
            }
            atomicAdd(&out[curb * OUTF + tid], acc);
        }
    }
}

extern "C" void kernel_launch(void* const* d_in, const int* in_sizes, int n_in,
                              void* d_out, int out_size, void* d_ws, size_t ws_size,
                              hipStream_t stream) {
    const float* x     = (const float*)d_in[0];
    const int*   ei    = (const int*)  d_in[1];
    const float* ea    = (const float*)d_in[2];
    const int*   batch = (const int*)  d_in[3];
    const float* W1    = (const float*)d_in[4];
    const float* b1    = (const float*)d_in[5];
    const float* Win   = (const float*)d_in[6];
    const float* b_in  = (const float*)d_in[7];
    const float* Wout  = (const float*)d_in[8];
    const float* b_out = (const float*)d_in[9];
    const float* W2    = (const float*)d_in[10];
    const float* b2    = (const float*)d_in[11];
    float* out = (float*)d_out;
    float* ws  = (float*)d_ws;

    // zero padded pck array (N lines of 64 B) before the cooperative pipeline
    hipMemsetAsync(ws + OFF_PCK, 0, (size_t)N * 64, stream);

    void* args[] = {&x, &ei, &ea, &batch, &W1, &b1, &Win, &b_in,
                    &Wout, &b_out, &W2, &b2, &ws, &out};
    hipLaunchCooperativeKernel((const void*)fused_kernel, dim3(256), dim3(1024),
                               args, 0, stream);
}

// Round 3
// 271.410 us; speedup vs baseline: 1.0877x; 1.0877x over previous
//
#include <hip/hip_runtime.h>
#include <hip/hip_bf16.h>

// Problem constants
constexpr int N = 4096, E = 131072, OUTF = 86, NB = 16, HEADS = 4, DH = 16;
constexpr int CAP = 128;   // padded bucket capacity per node (mean deg = 32)
constexpr int NSPLIT = 4, KEYS = N / NSPLIT;  // 1024 keys per attention split
constexpr int PCKS = 8;    // u64 stride per node in pck (64 B line per node)
constexpr int NBLK = 256;  // cooperative grid: 1 block/CU

typedef __attribute__((ext_vector_type(8))) short short8;
typedef __attribute__((ext_vector_type(4))) float f32x4;

constexpr unsigned long long PK_MASK = (1ULL << 40) - 1;  // low 40: fixed-point deg
constexpr float PK_SCALE = 1.0f / 16777216.0f;            // 2^-24

// Workspace offsets (float units, 16B-aligned)
constexpr size_t OFF_PCK   = 0;                           // N*PCKS u64 = 16N words
constexpr size_t OFF_INV   = OFF_PCK + 16 * (size_t)N;    // 16
constexpr size_t OFF_BUFA  = OFF_INV + 16;                // N*64 (xW1)
constexpr size_t OFF_QP    = OFF_BUFA + (size_t)N * 64;   // HEADS*N*16 bf16 = N*32 floats
constexpr size_t OFF_KP    = OFF_QP + (size_t)N * 32;
constexpr size_t OFF_VP    = OFF_KP + (size_t)N * 32;     // [h][16][N] bf16
constexpr size_t OFF_H2    = OFF_VP + (size_t)N * 32;     // N*86 (h2pre)
constexpr size_t OFF_EPAIR = OFF_H2 + (size_t)N * 86;     // N*CAP int2 {src, w}
constexpr size_t OFF_NORMV = OFF_EPAIR + (size_t)2 * N * CAP;  // N*CAP floats
constexpr size_t OFF_OPART = OFF_NORMV + (size_t)N * CAP; // HEADS*N*NSPLIT*16
constexpr size_t OFF_LPART = OFF_OPART + (size_t)HEADS * N * NSPLIT * 16;  // HEADS*N*NSPLIT

__device__ inline unsigned short f2bf(float f) {  // RNE float->bf16
    unsigned u = __builtin_bit_cast(unsigned, f);
    u += 0x7FFFu + ((u >> 16) & 1u);
    return (unsigned short)(u >> 16);
}

__device__ inline unsigned pk2bf(float a, float b) {  // packed RNE pair
    __hip_bfloat162 h2 = __float22bfloat162_rn(make_float2(a, b));
    union { __hip_bfloat162 h; unsigned u; } c;
    c.h = h2;
    return c.u;
}

__device__ inline float pk_deg(unsigned long long pk) {   // decode weighted degree
    return (float)(pk & PK_MASK) * PK_SCALE;
}

// Lightweight grid barrier. cnt lives in workspace (zeroed by the pck memset each
// iteration). Poll uses atomicAdd(cnt,0): an RMW always snoops the device coherence
// point, so no stale per-XCD L2 copy can deadlock the spin. __threadfence() gives
// release (pre-barrier writes flushed) / acquire (post-barrier reads see them);
// leader-thread fences cover the whole block: blockmates share the CU's L1 and the
// XCD's L2, and cache-maintenance ops are cache-wide.
__device__ inline void grid_bar(unsigned* cnt, unsigned target) {
    __syncthreads();
    if (threadIdx.x == 0) {
        __threadfence();
        atomicAdd(cnt, 1u);
        while (atomicAdd(cnt, 0u) < target)
            __builtin_amdgcn_s_sleep(2);
        __threadfence();
    }
    __syncthreads();
}

// ================= single fused kernel, hand-rolled grid barriers =================
// 256 blocks x 1024 threads (16 waves) = 4096 waves, 1 block/CU, all co-resident.
// Stage mapping (every stage needs exactly 4096 waves):
//   S0: edge bucket fill (waves 0-7) || gemm1 x@W1^T (waves 8-15) || out-init (block 0)
//   S1: agg1 + QKV pack (1 node/wave)
//   S2: MFMA flash attention (wave = (qtile, head, split))
//   S3: combine + Wout + W2 gemms (block = 16 rows)
//   S4: agg2 + per-graph reduce + atomics
// __launch_bounds__(1024, 4): min 4 waves/EU = our exact 1-block/CU residency ->
// VGPR cap 128 (not 64), restoring 8-deep gather ILP.
__global__ __launch_bounds__(1024, 4) void fused_kernel(
        const float* __restrict__ x, const int* __restrict__ ei,
        const float* __restrict__ ea, const int* __restrict__ batch,
        const float* __restrict__ W1, const float* __restrict__ b1,
        const float* __restrict__ Win, const float* __restrict__ b_in,
        const float* __restrict__ Wout, const float* __restrict__ b_out,
        const float* __restrict__ W2, const float* __restrict__ b2,
        float* __restrict__ ws, float* __restrict__ out) {
    __shared__ __align__(16) char smem[55552];

    const int tid = threadIdx.x, lane = tid & 63, wv = tid >> 6;
    const int gw = blockIdx.x * 16 + wv;          // global wave id [0, 4096)

    unsigned long long* pck = (unsigned long long*)(ws + OFF_PCK);
    unsigned* barcnt = (unsigned*)(ws + OFF_PCK) + 2;   // pck line-0 padding (memset-zeroed)
    int2*  epair = (int2*)(ws + OFF_EPAIR);
    float* bufA  = ws + OFF_BUFA;
    float* invcnt = ws + OFF_INV;

    // ---------------- S0: edge fill || gemm1 || out-init ----------------
    if (wv < 8) {
        // edge bucket fill: 512 thr/block * 256 blocks = 131072 = E
        int e = blockIdx.x * 512 + tid;
        int s = ei[e], d = ei[E + e];
        float w = ea[e];
        unsigned long long a = (1ULL << 40) + (unsigned long long)(unsigned)(w * 16777216.0f + 0.5f);
        unsigned long long o = atomicAdd(&pck[(size_t)d * PCKS], a);
        int p = (int)(o >> 40);
        if (p < CAP) epair[(size_t)d * CAP + p] = make_int2(s, __float_as_int(w));
    } else {
        // gemm1: 2048 waves * 2 rows = 4096 rows. Lane = output col.
        int gw2 = blockIdx.x * 8 + (wv - 8);
        int r0 = gw2 * 2, r1 = r0 + 1;
        float4 xa = ((const float4*)x)[(size_t)r0 * 16 + (lane & 15)];
        float4 xb = ((const float4*)x)[(size_t)r1 * 16 + (lane & 15)];
        float acc0 = 0.f, acc1 = 0.f;
#pragma unroll
        for (int k4 = 0; k4 < 16; ++k4) {
            float4 w4 = ((const float4*)W1)[lane * 16 + k4];  // W1[lane][4k4..] (L1-resident)
            float ax = __shfl(xa.x, k4), ay = __shfl(xa.y, k4);
            float az = __shfl(xa.z, k4), aw = __shfl(xa.w, k4);
            acc0 += ax * w4.x + ay * w4.y + az * w4.z + aw * w4.w;
            float bx = __shfl(xb.x, k4), by = __shfl(xb.y, k4);
            float bz = __shfl(xb.z, k4), bw = __shfl(xb.w, k4);
            acc1 += bx * w4.x + by * w4.y + bz * w4.z + bw * w4.w;
        }
        bufA[(size_t)r0 * 64 + lane] = acc0;
        bufA[(size_t)r1 * 64 + lane] = acc1;
    }
    if (blockIdx.x == 0) {
        // out-init: parallel binary searches for graph boundaries, then broadcast
        int* bnd = (int*)smem;
        __syncthreads();
        if (tid <= NB) {
            int b = tid, lo = 0, hi = N;
            while (lo < hi) { int m = (lo + hi) >> 1; if (batch[m] < b) lo = m + 1; else hi = m; }
            bnd[tid] = lo;
        }
        __syncthreads();
        if (tid < NB) {
            int cnt = bnd[tid + 1] - bnd[tid];
            invcnt[tid] = cnt > 0 ? 1.0f / (float)cnt : 0.0f;
        }
        for (int idx = tid; idx < NB * OUTF; idx += 1024) {
            int b = idx / OUTF;
            int cnt = bnd[b + 1] - bnd[b];
            out[idx] = cnt > 0 ? b2[idx - b * OUTF] : 0.0f;
        }
    }
    grid_bar(barcnt, 1 * NBLK);

    // ---------------- S1: agg1(+b1,ReLU) -> QKV gemm + bf16 pack ----------------
    {
        float4* Ws4 = (float4*)smem;               // [k4][c] pad 200: 51200 B
        float*  Af  = (float*)(smem + 51200);      // 16*68 floats: 4352 B
        float*       normv = ws + OFF_NORMV;
        unsigned short* Qp = (unsigned short*)(ws + OFF_QP);
        unsigned short* Kp = (unsigned short*)(ws + OFF_KP);
        unsigned short* Vp = (unsigned short*)(ws + OFF_VP);

        for (int idx = tid; idx < 192 * 16; idx += 1024) {
            int c = idx >> 4, k4 = idx & 15;
            Ws4[k4 * 200 + c] = ((const float4*)Win)[idx];
        }

        const int node = gw;
        {
            const unsigned long long pkn = pck[(size_t)node * PCKS];
            const float di = rsqrtf(pk_deg(pkn) + 1.0f);   // self-loop: deg+1
            float acc0 = (di * di) * bufA[(size_t)node * 64 + lane];
            float acc1 = 0.f, acc2 = 0.f, acc3 = 0.f;
            const int cnt = min((int)(pkn >> 40), CAP);
            const int2* pe = epair + (size_t)node * CAP;
            for (int base = 0; base < cnt; base += 64) {
                int rem = cnt - base;
                int   sl = 0;
                float nl = 0.f;
                if (lane < rem) {
                    int2 e = pe[base + lane];
                    sl = e.x;
                    float w = __int_as_float(e.y);
                    nl = rsqrtf(pk_deg(pck[(size_t)sl * PCKS]) + 1.0f) * w * di;
                    normv[(size_t)node * CAP + base + lane] = nl;   // for S4
                }
                int m = rem < 64 ? rem : 64;
                int j = 0;
                for (; j + 8 <= m; j += 8) {
                    int   s0 = __shfl(sl, j),     s1 = __shfl(sl, j + 1);
                    int   s2 = __shfl(sl, j + 2), s3 = __shfl(sl, j + 3);
                    int   s4 = __shfl(sl, j + 4), s5 = __shfl(sl, j + 5);
                    int   s6 = __shfl(sl, j + 6), s7 = __shfl(sl, j + 7);
                    float n0 = __shfl(nl, j),     n1 = __shfl(nl, j + 1);
                    float n2 = __shfl(nl, j + 2), n3 = __shfl(nl, j + 3);
                    float n4 = __shfl(nl, j + 4), n5 = __shfl(nl, j + 5);
                    float n6 = __shfl(nl, j + 6), n7 = __shfl(nl, j + 7);
                    float v0 = bufA[(size_t)s0 * 64 + lane], v1 = bufA[(size_t)s1 * 64 + lane];
                    float v2 = bufA[(size_t)s2 * 64 + lane], v3 = bufA[(size_t)s3 * 64 + lane];
                    float v4 = bufA[(size_t)s4 * 64 + lane], v5 = bufA[(size_t)s5 * 64 + lane];
                    float v6 = bufA[(size_t)s6 * 64 + lane], v7 = bufA[(size_t)s7 * 64 + lane];
                    acc0 += n0 * v0; acc1 += n1 * v1; acc2 += n2 * v2; acc3 += n3 * v3;
                    acc0 += n4 * v4; acc1 += n5 * v5; acc2 += n6 * v6; acc3 += n7 * v7;
                }
                for (; j + 4 <= m; j += 4) {
                    int   s0 = __shfl(sl, j),     s1 = __shfl(sl, j + 1);
                    int   s2 = __shfl(sl, j + 2), s3 = __shfl(sl, j + 3);
                    float n0 = __shfl(nl, j),     n1 = __shfl(nl, j + 1);
                    float n2 = __shfl(nl, j + 2), n3 = __shfl(nl, j + 3);
                    acc0 += n0 * bufA[(size_t)s0 * 64 + lane];
                    acc1 += n1 * bufA[(size_t)s1 * 64 + lane];
                    acc2 += n2 * bufA[(size_t)s2 * 64 + lane];
                    acc3 += n3 * bufA[(size_t)s3 * 64 + lane];
                }
                for (; j < m; ++j) {
                    int   s0 = __shfl(sl, j);
                    float n0 = __shfl(nl, j);
                    acc0 += n0 * bufA[(size_t)s0 * 64 + lane];
                }
            }
            Af[wv * 68 + lane] = fmaxf((acc0 + acc1) + (acc2 + acc3) + b1[lane], 0.0f);
        }
        __syncthreads();

        // QKV: wave wv computes row (node); lane handles cols {lane, lane+64, lane+128}
        {
            const float4* Af4 = (const float4*)Af;
            float acc[3];
#pragma unroll
            for (int i = 0; i < 3; ++i) acc[i] = b_in[lane + 64 * i];
#pragma unroll
            for (int k4 = 0; k4 < 16; ++k4) {
                float4 a = Af4[wv * 17 + k4];          // wave-broadcast
#pragma unroll
                for (int i = 0; i < 3; ++i) {
                    float4 w = Ws4[k4 * 200 + lane + 64 * i];  // lane-consecutive
                    acc[i] += a.x * w.x + a.y * w.y + a.z * w.z + a.w * w.w;
                }
            }
            const int row = node;
#pragma unroll
            for (int i = 0; i < 3; ++i) {
                int c = lane + 64 * i;
                float v = acc[i];
                if (c < 64) {
                    int h = c >> 4, d = c & 15;
                    Qp[((size_t)h * N + row) * 16 + d] = f2bf(v * 0.25f);  // 1/sqrt(DH)
                } else if (c < 128) {
                    int c2 = c - 64, h = c2 >> 4, d = c2 & 15;
                    Kp[((size_t)h * N + row) * 16 + d] = f2bf(v);
                } else {
                    int c2 = c - 128, h = c2 >> 4, d = c2 & 15;
                    Vp[((size_t)h * 16 + d) * N + row] = f2bf(v);
                }
            }
        }
    }
    grid_bar(barcnt, 2 * NBLK);

    // ---------------- S2: MFMA flash attention, KV-split ----------------
    {
        unsigned short* Plds = (unsigned short*)smem;   // 16 waves * 640 ushort = 20480 B
        const unsigned short* Qp = (const unsigned short*)(ws + OFF_QP);
        const unsigned short* Kp = (const unsigned short*)(ws + OFF_KP);
        const unsigned short* Vp = (const unsigned short*)(ws + OFF_VP);
        float* opart = ws + OFF_OPART;
        float* lpart = ws + OFF_LPART;

        const int qt = gw & 255;            // 256 q-tiles
        const int h  = (gw >> 8) & 3;       // 4 heads
        const int sp = gw >> 10;            // NSPLIT=4 splits
        const int k0 = sp * KEYS;
        const int q15 = lane & 15, quad = lane >> 4;
        const int qbase = qt * 16;

        short8 qf = {};
        if (quad < 2)
            qf = *(const short8*)&Qp[((size_t)h * N + qbase + q15) * 16 + quad * 8];

        f32x4 O = {0.f, 0.f, 0.f, 0.f};
        float l = 0.f;
        unsigned short* Pw = &Plds[wv * 640];
        const unsigned short* Kh = Kp + (size_t)h * N * 16;
        const unsigned short* Vh = Vp + ((size_t)h * 16 + q15) * N + k0;

#pragma unroll 2
        for (int ch = 0; ch < KEYS / 32; ++ch) {
#pragma unroll
            for (int t = 0; t < 2; ++t) {
                short8 kf = {};
                if (quad < 2)
                    kf = *(const short8*)&Kh[(size_t)(k0 + ch * 32 + t * 16 + q15) * 16 + quad * 8];
                f32x4 zero = {0.f, 0.f, 0.f, 0.f};
                __builtin_amdgcn_s_setprio(1);
                f32x4 s = __builtin_amdgcn_mfma_f32_16x16x32_bf16(kf, qf, zero, 0, 0, 0);
                __builtin_amdgcn_s_setprio(0);
                // C-layout: col=query=lane&15, row=key=quad*4+reg
                float p0 = __expf(s[0]), p1 = __expf(s[1]), p2 = __expf(s[2]), p3 = __expf(s[3]);
                l += (p0 + p1) + (p2 + p3);
                uint2 pk;
                pk.x = pk2bf(p0, p1);
                pk.y = pk2bf(p2, p3);
                *(uint2*)&Pw[q15 * 40 + t * 16 + quad * 4] = pk;
            }
            asm volatile("s_waitcnt lgkmcnt(0)" ::: "memory");
            short8 pf = *(const short8*)&Pw[q15 * 40 + quad * 8];   // A: m=query, k=key
            short8 vf = *(const short8*)&Vh[ch * 32 + quad * 8];    // B: n=dh,    k=key
            __builtin_amdgcn_s_setprio(1);
            O = __builtin_amdgcn_mfma_f32_16x16x32_bf16(pf, vf, O, 0, 0, 0);
            __builtin_amdgcn_s_setprio(0);
        }

        l += __shfl_xor(l, 16);
        l += __shfl_xor(l, 32);
        if (lane < 16)
            lpart[((size_t)h * N + qbase + q15) * NSPLIT + sp] = l;
#pragma unroll
        for (int r = 0; r < 4; ++r) {
            int query = qbase + quad * 4 + r;
            opart[(((size_t)h * N + query) * NSPLIT + sp) * 16 + q15] = O[r];
        }
    }
    grid_bar(barcnt, 3 * NBLK);

    // ---------------- S3: combine -> Wout gemm -> W2 gemm -> h2pre ----------------
    {
        float4* WoS = (float4*)smem;                       // 64*17 f4 = 17408 B
        float4* W2S = (float4*)(smem + 17408);             // 86*17 f4 = 23392 B
        float*  o_sh = (float*)(smem + 17408 + 23392);     // 16*68 = 4352 B
        float*  Bf   = (float*)(smem + 17408 + 23392 + 4352);  // 4352 B

        const float* opart = ws + OFF_OPART;
        const float* lpart = ws + OFF_LPART;
        float* h2pre = ws + OFF_H2;
        const int qbase = blockIdx.x * 16;

        if (tid < 64 * 16)
            WoS[(tid >> 4) * 17 + (tid & 15)] = ((const float4*)Wout)[tid];
        for (int idx = tid; idx < 86 * 16; idx += 1024)
            W2S[(idx >> 4) * 17 + (idx & 15)] = ((const float4*)W2)[idx];

        // combine: one (row, feat) per thread
        {
            int r = tid >> 6, f = tid & 63;
            int h = f >> 4, d = f & 15;
            size_t base = ((size_t)h * N + qbase + r) * NSPLIT;
            float L = 0.f, acc = 0.f;
#pragma unroll
            for (int s = 0; s < NSPLIT; ++s) {
                L += lpart[base + s];
                acc += opart[(base + s) * 16 + d];
            }
            o_sh[r * 68 + f] = acc / L;
        }
        __syncthreads();
        // Wout gemm: one (row, col) per thread
        float bacc;
        {
            int r = tid & 15, c = tid >> 4;
            float4* o4 = (float4*)o_sh;
            bacc = b_out[c];
#pragma unroll
            for (int k4 = 0; k4 < 16; ++k4) {
                float4 a = o4[r * 17 + k4];
                float4 w = WoS[c * 17 + k4];
                bacc += a.x * w.x + a.y * w.y + a.z * w.z + a.w * w.w;
            }
        }
        __syncthreads();   // o_sh reads done before Bf write
        {
            int r = tid & 15, c = tid >> 4;
            Bf[r * 68 + c] = bacc;
        }
        __syncthreads();
        // W2 gemm: 16 rows x 86 cols, threads cover (r, c) and (r, c+64)
        {
            int r = tid & 15, c0 = tid >> 4;
            float4* B4 = (float4*)Bf;
#pragma unroll
            for (int i = 0; i < 2; ++i) {
                int c = c0 + 64 * i;
                if (c < OUTF) {
                    float acc = 0.f;
#pragma unroll
                    for (int k4 = 0; k4 < 16; ++k4) {
                        float4 a = B4[r * 17 + k4];
                        float4 w = W2S[c * 17 + k4];
                        acc += a.x * w.x + a.y * w.y + a.z * w.z + a.w * w.w;
                    }
                    h2pre[(size_t)(qbase + r) * OUTF + c] = acc;
                }
            }
        }
    }
    grid_bar(barcnt, 4 * NBLK);

    // ---------------- S4: agg2 + per-graph pre-reduction + atomics ----------------
    {
        float (*vec)[88] = (float (*)[88])smem;        // 16*88*4 = 5632 B
        int* bix = (int*)(smem + 5632);

        const float* normv = ws + OFF_NORMV;
        const float* h2pre = ws + OFF_H2;

        const int node = gw;
        const bool hi2 = lane < (OUTF - 64);
        const int b = batch[node];
        const float inv = invcnt[b];
        const unsigned long long pkn = pck[(size_t)node * PCKS];
        const float di2 = 1.0f / (pk_deg(pkn) + 1.0f);
        const float* Hn = h2pre + (size_t)node * OUTF;
        float a0 = di2 * Hn[lane],                  a1 = 0.f, a2 = 0.f, a3 = 0.f;
        float c0 = hi2 ? di2 * Hn[64 + lane] : 0.f, c1 = 0.f, c2 = 0.f, c3 = 0.f;
        const int cnt = min((int)(pkn >> 40), CAP);
        const int2* pe = epair + (size_t)node * CAP;

        for (int base = 0; base < cnt; base += 64) {
            int rem = cnt - base;
            int   sl = 0;
            float nl = 0.f;
            if (lane < rem) {
                sl = pe[base + lane].x;
                nl = normv[(size_t)node * CAP + base + lane];
            }
            int m = rem < 64 ? rem : 64;
            int j = 0;
            for (; j + 8 <= m; j += 8) {
                int   s0 = __shfl(sl, j),     s1 = __shfl(sl, j + 1);
                int   s2 = __shfl(sl, j + 2), s3 = __shfl(sl, j + 3);
                int   s4 = __shfl(sl, j + 4), s5 = __shfl(sl, j + 5);
                int   s6 = __shfl(sl, j + 6), s7 = __shfl(sl, j + 7);
                float n0 = __shfl(nl, j),     n1 = __shfl(nl, j + 1);
                float n2 = __shfl(nl, j + 2), n3 = __shfl(nl, j + 3);
                float n4 = __shfl(nl, j + 4), n5 = __shfl(nl, j + 5);
                float n6 = __shfl(nl, j + 6), n7 = __shfl(nl, j + 7);
                const float* H0 = h2pre + (size_t)s0 * OUTF;
                const float* H1 = h2pre + (size_t)s1 * OUTF;
                const float* H2 = h2pre + (size_t)s2 * OUTF;
                const float* H3 = h2pre + (size_t)s3 * OUTF;
                const float* H4 = h2pre + (size_t)s4 * OUTF;
                const float* H5 = h2pre + (size_t)s5 * OUTF;
                const float* H6 = h2pre + (size_t)s6 * OUTF;
                const float* H7 = h2pre + (size_t)s7 * OUTF;
                float v0 = H0[lane], v1 = H1[lane], v2 = H2[lane], v3 = H3[lane];
                float v4 = H4[lane], v5 = H5[lane], v6 = H6[lane], v7 = H7[lane];
                a0 += n0 * v0; a1 += n1 * v1; a2 += n2 * v2; a3 += n3 * v3;
                a0 += n4 * v4; a1 += n5 * v5; a2 += n6 * v6; a3 += n7 * v7;
                if (hi2) {
                    float w0 = H0[64 + lane], w1 = H1[64 + lane];
                    float w2 = H2[64 + lane], w3 = H3[64 + lane];
                    float w4 = H4[64 + lane], w5 = H5[64 + lane];
                    float w6 = H6[64 + lane], w7 = H7[64 + lane];
                    c0 += n0 * w0; c1 += n1 * w1; c2 += n2 * w2; c3 += n3 * w3;
                    c0 += n4 * w4; c1 += n5 * w5; c2 += n6 * w6; c3 += n7 * w7;
                }
            }
            for (; j + 4 <= m; j += 4) {
                int   s0 = __shfl(sl, j),     s1 = __shfl(sl, j + 1);
                int   s2 = __shfl(sl, j + 2), s3 = __shfl(sl, j + 3);
                float n0 = __shfl(nl, j),     n1 = __shfl(nl, j + 1);
                float n2 = __shfl(nl, j + 2), n3 = __shfl(nl, j + 3);
                const float* H0 = h2pre + (size_t)s0 * OUTF;
                const float* H1 = h2pre + (size_t)s1 * OUTF;
                const float* H2 = h2pre + (size_t)s2 * OUTF;
                const float* H3 = h2pre + (size_t)s3 * OUTF;
                a0 += n0 * H0[lane]; if (hi2) c0 += n0 * H0[64 + lane];
                a1 += n1 * H1[lane]; if (hi2) c1 += n1 * H1[64 + lane];
                a2 += n2 * H2[lane]; if (hi2) c2 += n2 * H2[64 + lane];
                a3 += n3 * H3[lane]; if (hi2) c3 += n3 * H3[64 + lane];
            }
            for (; j < m; ++j) {
                int   s0 = __shfl(sl, j);
                float n0 = __shfl(nl, j);
                const float* H0 = h2pre + (size_t)s0 * OUTF;
                a0 += n0 * H0[lane];
                if (hi2) c0 += n0 * H0[64 + lane];
            }
        }
        vec[wv][lane] = ((a0 + a1) + (a2 + a3)) * inv;
        if (hi2) vec[wv][64 + lane] = ((c0 + c1) + (c2 + c3)) * inv;
        if (lane == 0) bix[wv] = b;
        __syncthreads();
        // per-graph pre-reduction over the 16 sorted nodes: 1 atomic per (graph, feat)
        if (tid < OUTF) {
            int curb = bix[0];
            float acc = 0.f;
#pragma unroll
            for (int w = 0; w < 16; ++w) {
                int bw = bix[w];
                if (bw != curb) {
                    atomicAdd(&out[curb * OUTF + tid], acc);
                    curb = bw; acc = 0.f;
                }
                acc += vec[w][tid];
            }
            atomicAdd(&out[curb * OUTF + tid], acc);
        }
    }
}

extern "C" void kernel_launch(void* const* d_in, const int* in_sizes, int n_in,
                              void* d_out, int out_size, void* d_ws, size_t ws_size,
                              hipStream_t stream) {
    const float* x     = (const float*)d_in[0];
    const int*   ei    = (const int*)  d_in[1];
    const float* ea    = (const float*)d_in[2];
    const int*   batch = (const int*)  d_in[3];
    const float* W1    = (const float*)d_in[4];
    const float* b1    = (const float*)d_in[5];
    const float* Win   = (const float*)d_in[6];
    const float* b_in  = (const float*)d_in[7];
    const float* Wout  = (const float*)d_in[8];
    const float* b_out = (const float*)d_in[9];
    const float* W2    = (const float*)d_in[10];
    const float* b2    = (const float*)d_in[11];
    float* out = (float*)d_out;
    float* ws  = (float*)d_ws;

    // zero padded pck array (N lines of 64 B) — also zeroes the grid-barrier counter
    hipMemsetAsync(ws + OFF_PCK, 0, (size_t)N * 64, stream);

    void* args[] = {&x, &ei, &ea, &batch, &W1, &b1, &Win, &b_in,
                    &Wout, &b_out, &W2, &b2, &ws, &out};
    hipLaunchCooperativeKernel((const void*)fused_kernel, dim3(NBLK), dim3(1024),
                               args, 0, stream);
}

// Round 5
// 148.768 us; speedup vs baseline: 1.9844x; 1.8244x over previous
//
#include <hip/hip_runtime.h>
#include <hip/hip_bf16.h>

// Problem constants
constexpr int N = 4096, E = 131072, OUTF = 86, NB = 16, HEADS = 4, DH = 16;
constexpr int CAP = 128;   // padded bucket capacity per node (mean deg = 32)
constexpr int NSPLIT = 4, KEYS = N / NSPLIT;  // 1024 keys per attention split
constexpr int PCKS = 8;    // u64 stride per node in pck (64 B line per node)

typedef __attribute__((ext_vector_type(8))) short short8;
typedef __attribute__((ext_vector_type(4))) float f32x4;

constexpr unsigned long long PK_MASK = (1ULL << 40) - 1;  // low 40: fixed-point deg
constexpr float PK_SCALE = 1.0f / 16777216.0f;            // 2^-24

// Workspace offsets (float units, 16B-aligned)
constexpr size_t OFF_PCK   = 0;                           // N*PCKS u64 = 16N words
constexpr size_t OFF_INV   = OFF_PCK + 16 * (size_t)N;    // 16
constexpr size_t OFF_BUFA  = OFF_INV + 16;                // N*64 (xW1)
constexpr size_t OFF_QP    = OFF_BUFA + (size_t)N * 64;   // HEADS*N*16 bf16 = N*32 floats
constexpr size_t OFF_KP    = OFF_QP + (size_t)N * 32;
constexpr size_t OFF_VP    = OFF_KP + (size_t)N * 32;     // [h][16][N] bf16
constexpr size_t OFF_H2    = OFF_VP + (size_t)N * 32;     // N*86 (h2pre)
constexpr size_t OFF_EPAIR = OFF_H2 + (size_t)N * 86;     // N*CAP int2 {src, w}
constexpr size_t OFF_NORMV = OFF_EPAIR + (size_t)2 * N * CAP;  // N*CAP floats
constexpr size_t OFF_OPART = OFF_NORMV + (size_t)N * CAP; // HEADS*N*NSPLIT*16
constexpr size_t OFF_LPART = OFF_OPART + (size_t)HEADS * N * NSPLIT * 16;  // HEADS*N*NSPLIT

__device__ inline unsigned short f2bf(float f) {  // RNE float->bf16
    unsigned u = __builtin_bit_cast(unsigned, f);
    u += 0x7FFFu + ((u >> 16) & 1u);
    return (unsigned short)(u >> 16);
}

__device__ inline unsigned pk2bf(float a, float b) {  // packed RNE pair
    __hip_bfloat162 h2 = __float22bfloat162_rn(make_float2(a, b));
    union { __hip_bfloat162 h; unsigned u; } c;
    c.h = h2;
    return c.u;
}

__device__ inline float pk_deg(unsigned long long pk) {   // decode weighted degree
    return (float)(pk & PK_MASK) * PK_SCALE;
}

// ===== D1: gemm1 (blk<256) || edge bucket fill x2 (256..511) || out-init (512) =====
__global__ __launch_bounds__(256) void d1_kernel(const float* __restrict__ x,
        const float* __restrict__ W1, const int* __restrict__ ei,
        const float* __restrict__ ea, const int* __restrict__ batch,
        const float* __restrict__ b2, float* __restrict__ ws, float* __restrict__ out) {
    __shared__ float4 Ws4[64 * 17];
    __shared__ float4 As4[16 * 17];
    __shared__ int bnd[NB + 1];
    int blk = blockIdx.x, tid = threadIdx.x;
    if (blk < 256) {
        float* bufA = ws + OFF_BUFA;
        for (int idx = tid; idx < 64 * 16; idx += 256)
            Ws4[(idx >> 4) * 17 + (idx & 15)] = ((const float4*)W1)[idx];
        {
            int r = tid >> 4, k4 = tid & 15;
            As4[r * 17 + k4] = ((const float4*)x)[(size_t)(blk * 16 + r) * 16 + k4];
        }
        __syncthreads();
        int r2 = tid & 7, cg = tid >> 3;
        float acc[2][2] = {};
#pragma unroll
        for (int k4 = 0; k4 < 16; ++k4) {
            float4 a0 = As4[r2 * 17 + k4], a1 = As4[(r2 + 8) * 17 + k4];
#pragma unroll
            for (int i = 0; i < 2; ++i) {
                float4 w = Ws4[(cg + 32 * i) * 17 + k4];
                acc[0][i] += a0.x * w.x + a0.y * w.y + a0.z * w.z + a0.w * w.w;
                acc[1][i] += a1.x * w.x + a1.y * w.y + a1.z * w.z + a1.w * w.w;
            }
        }
#pragma unroll
        for (int j = 0; j < 2; ++j)
#pragma unroll
            for (int i = 0; i < 2; ++i)
                bufA[(size_t)(blk * 16 + r2 + 8 * j) * 64 + cg + 32 * i] = acc[j][i];
    } else if (blk < 512) {
        unsigned long long* pck = (unsigned long long*)(ws + OFF_PCK);
        int2* epair = (int2*)(ws + OFF_EPAIR);
        int f = (blk - 256) * 256 + tid;          // [0, E/2)
        int e0 = f, e1 = f + E / 2;
        int s0 = ei[e0], d0 = ei[E + e0];
        int s1 = ei[e1], d1 = ei[E + e1];
        float w0 = ea[e0], w1 = ea[e1];
        unsigned long long a0 = (1ULL << 40) + (unsigned long long)(unsigned)(w0 * 16777216.0f + 0.5f);
        unsigned long long a1 = (1ULL << 40) + (unsigned long long)(unsigned)(w1 * 16777216.0f + 0.5f);
        unsigned long long o0 = atomicAdd(&pck[(size_t)d0 * PCKS], a0);
        unsigned long long o1 = atomicAdd(&pck[(size_t)d1 * PCKS], a1);
        int p0 = (int)(o0 >> 40), p1 = (int)(o1 >> 40);
        if (p0 < CAP) epair[(size_t)d0 * CAP + p0] = make_int2(s0, __float_as_int(w0));
        if (p1 < CAP) epair[(size_t)d1 * CAP + p1] = make_int2(s1, __float_as_int(w1));
    } else {
        // out-init: 17 PARALLEL binary searches (one per graph boundary), then broadcast
        float* invcnt = ws + OFF_INV;
        if (tid <= NB) {
            int b = tid, lo = 0, hi = N;
            while (lo < hi) { int m = (lo + hi) >> 1; if (batch[m] < b) lo = m + 1; else hi = m; }
            bnd[tid] = lo;
        }
        __syncthreads();
        if (tid < NB) {
            int cnt = bnd[tid + 1] - bnd[tid];
            invcnt[tid] = cnt > 0 ? 1.0f / (float)cnt : 0.0f;
        }
        for (int idx = tid; idx < NB * OUTF; idx += 256) {
            int b = idx / OUTF;
            int cnt = bnd[b + 1] - bnd[b];
            out[idx] = cnt > 0 ? b2[idx - b * OUTF] : 0.0f;
        }
    }
}

// ===== D23: fused agg1(+b1,ReLU in LDS) -> QKV gemm + bf16 pack =====
__global__ __launch_bounds__(1024) void d23_kernel(const float* __restrict__ Win,
        const float* __restrict__ b1, const float* __restrict__ b_in,
        float* __restrict__ ws) {
    __shared__ float4 Ws4[16 * 200];   // [k4][c] (c<192, pad 200): reads lane-consecutive
    __shared__ float  Af[16 * 68];     // h1 rows (stride 68 floats = 17 float4)

    const unsigned long long* pck = (const unsigned long long*)(ws + OFF_PCK);
    const int2*  epair = (const int2*)(ws + OFF_EPAIR);
    float*       normv = ws + OFF_NORMV;
    const float* bufA  = ws + OFF_BUFA;
    unsigned short* Qp = (unsigned short*)(ws + OFF_QP);
    unsigned short* Kp = (unsigned short*)(ws + OFF_KP);
    unsigned short* Vp = (unsigned short*)(ws + OFF_VP);

    const int tid = threadIdx.x, lane = tid & 63, wv = tid >> 6;
    for (int idx = tid; idx < 192 * 16; idx += 1024) {
        int c = idx >> 4, k4 = idx & 15;
        Ws4[k4 * 200 + c] = ((const float4*)Win)[idx];
    }

    // phase 1: wave wv aggregates node
    const int node = blockIdx.x * 16 + wv;
    {
        const unsigned long long pkn = pck[(size_t)node * PCKS];
        const float di = rsqrtf(pk_deg(pkn) + 1.0f);   // self-loop: deg+1
        float acc0 = (di * di) * bufA[(size_t)node * 64 + lane];
        float acc1 = 0.f, acc2 = 0.f, acc3 = 0.f;
        const int cnt = min((int)(pkn >> 40), CAP);
        const int2* pe = epair + (size_t)node * CAP;
        for (int base = 0; base < cnt; base += 64) {
            int rem = cnt - base;
            int   sl = 0;
            float nl = 0.f;
            if (lane < rem) {                      // coalesced 8B load per lane
                int2 e = pe[base + lane];
                sl = e.x;
                float w = __int_as_float(e.y);
                nl = rsqrtf(pk_deg(pck[(size_t)sl * PCKS]) + 1.0f) * w * di;
                normv[(size_t)node * CAP + base + lane] = nl;   // for D5
            }
            int m = rem < 64 ? rem : 64;
            int j = 0;
            for (; j + 8 <= m; j += 8) {           // 8 row-gathers in flight
                int   s0 = __shfl(sl, j),     s1 = __shfl(sl, j + 1);
                int   s2 = __shfl(sl, j + 2), s3 = __shfl(sl, j + 3);
                int   s4 = __shfl(sl, j + 4), s5 = __shfl(sl, j + 5);
                int   s6 = __shfl(sl, j + 6), s7 = __shfl(sl, j + 7);
                float n0 = __shfl(nl, j),     n1 = __shfl(nl, j + 1);
                float n2 = __shfl(nl, j + 2), n3 = __shfl(nl, j + 3);
                float n4 = __shfl(nl, j + 4), n5 = __shfl(nl, j + 5);
                float n6 = __shfl(nl, j + 6), n7 = __shfl(nl, j + 7);
                float v0 = bufA[(size_t)s0 * 64 + lane], v1 = bufA[(size_t)s1 * 64 + lane];
                float v2 = bufA[(size_t)s2 * 64 + lane], v3 = bufA[(size_t)s3 * 64 + lane];
                float v4 = bufA[(size_t)s4 * 64 + lane], v5 = bufA[(size_t)s5 * 64 + lane];
                float v6 = bufA[(size_t)s6 * 64 + lane], v7 = bufA[(size_t)s7 * 64 + lane];
                acc0 += n0 * v0; acc1 += n1 * v1; acc2 += n2 * v2; acc3 += n3 * v3;
                acc0 += n4 * v4; acc1 += n5 * v5; acc2 += n6 * v6; acc3 += n7 * v7;
            }
            for (; j + 4 <= m; j += 4) {
                int   s0 = __shfl(sl, j),     s1 = __shfl(sl, j + 1);
                int   s2 = __shfl(sl, j + 2), s3 = __shfl(sl, j + 3);
                float n0 = __shfl(nl, j),     n1 = __shfl(nl, j + 1);
                float n2 = __shfl(nl, j + 2), n3 = __shfl(nl, j + 3);
                acc0 += n0 * bufA[(size_t)s0 * 64 + lane];
                acc1 += n1 * bufA[(size_t)s1 * 64 + lane];
                acc2 += n2 * bufA[(size_t)s2 * 64 + lane];
                acc3 += n3 * bufA[(size_t)s3 * 64 + lane];
            }
            for (; j < m; ++j) {
                int   s0 = __shfl(sl, j);
                float n0 = __shfl(nl, j);
                acc0 += n0 * bufA[(size_t)s0 * 64 + lane];
            }
        }
        Af[wv * 68 + lane] = fmaxf((acc0 + acc1) + (acc2 + acc3) + b1[lane], 0.0f);
    }
    __syncthreads();

    // phase 2: wave wv computes QKV row (node); lane handles cols {lane, lane+64, lane+128}
    {
        const float4* Af4 = (const float4*)Af;
        float acc[3];
#pragma unroll
        for (int i = 0; i < 3; ++i) acc[i] = b_in[lane + 64 * i];
#pragma unroll
        for (int k4 = 0; k4 < 16; ++k4) {
            float4 a = Af4[wv * 17 + k4];          // wave-broadcast
#pragma unroll
            for (int i = 0; i < 3; ++i) {
                float4 w = Ws4[k4 * 200 + lane + 64 * i];  // lane-consecutive
                acc[i] += a.x * w.x + a.y * w.y + a.z * w.z + a.w * w.w;
            }
        }
        const int row = node;
#pragma unroll
        for (int i = 0; i < 3; ++i) {
            int c = lane + 64 * i;
            float v = acc[i];
            if (c < 64) {
                int h = c >> 4, d = c & 15;
                Qp[((size_t)h * N + row) * 16 + d] = f2bf(v * 0.25f);  // 1/sqrt(DH)
            } else if (c < 128) {
                int c2 = c - 64, h = c2 >> 4, d = c2 & 15;
                Kp[((size_t)h * N + row) * 16 + d] = f2bf(v);
            } else {
                int c2 = c - 128, h = c2 >> 4, d = c2 & 15;
                Vp[((size_t)h * 16 + d) * N + row] = f2bf(v);
            }
        }
    }
}

// ===== attn: MFMA flash attention, KV-split, block-shared K/V in LDS =====
// 1024-thread blocks = 16 waves = 16 q-tiles, all sharing one (h, sp) K/V stream.
// K/V staged cooperatively in 64-key slabs: cuts K/V L2 traffic 16x vs per-wave
// streaming (268 MB -> 17 MB) and converts latency-exposed global loads to LDS.
// Strides: Ksh 24 shorts (48 B), Vsh 80 shorts (160 B) -> all short8 reads 16B-aligned.
__global__ __launch_bounds__(1024) void attn_kernel(const float* __restrict__ ws_c,
        float* __restrict__ ws) {
    __shared__ __align__(16) unsigned short Ksh[64 * 24];   // [key][dh]
    __shared__ __align__(16) unsigned short Vsh[16 * 80];   // [dh][key]
    __shared__ __align__(16) unsigned short Plds[16 * 640]; // per-wave P roundtrip

    const unsigned short* Qp = (const unsigned short*)(ws_c + OFF_QP);
    const unsigned short* Kp = (const unsigned short*)(ws_c + OFF_KP);
    const unsigned short* Vp = (const unsigned short*)(ws_c + OFF_VP);
    float* opart = ws + OFF_OPART;
    float* lpart = ws + OFF_LPART;

    const int h  = blockIdx.y;
    const int sp = blockIdx.z;
    const int k0 = sp * KEYS;
    const int tid = threadIdx.x;
    const int lane = tid & 63, wv = tid >> 6;
    const int q15 = lane & 15, quad = lane >> 4;

    const int qbase = blockIdx.x * 256 + wv * 16;
    short8 qf = {};
    if (quad < 2)
        qf = *(const short8*)&Qp[((size_t)h * N + qbase + q15) * 16 + quad * 8];

    f32x4 O = {0.f, 0.f, 0.f, 0.f};
    float l = 0.f;
    unsigned short* Pw = &Plds[wv * 640];
    const unsigned short* Kh = Kp + (size_t)h * N * 16;
    const unsigned short* Vh = Vp + (size_t)h * 16 * N;

    // staging index precompute
    const int krow = tid >> 3, kp = tid & 7;       // K: threads 0..511, 8 per 16-dh key row
    const int vd = tid >> 6, vk = tid & 63;        // V: 64 threads per dh row

    for (int s = 0; s < KEYS / 64; ++s) {          // 16 slabs of 64 keys
        __syncthreads();
        // stage K slab: 64 keys x 16 dh (threads 0..511, coalesced 2 KB)
        if (tid < 512)
            *(short2*)&Ksh[krow * 24 + kp * 2] =
                *(const short2*)&Kh[(size_t)(k0 + s * 64 + krow) * 16 + kp * 2];
        // stage V slab: 16 dh x 64 keys (all 1024 threads, coalesced 2 KB)
        Vsh[vd * 80 + vk] = Vh[(size_t)vd * N + k0 + s * 64 + vk];
        __syncthreads();
#pragma unroll
        for (int t2 = 0; t2 < 2; ++t2) {           // two 32-key chunks per slab
#pragma unroll
            for (int t = 0; t < 2; ++t) {
                short8 kf = {};
                if (quad < 2)
                    kf = *(const short8*)&Ksh[(t2 * 32 + t * 16 + q15) * 24 + quad * 8];
                f32x4 zero = {0.f, 0.f, 0.f, 0.f};
                f32x4 sc = __builtin_amdgcn_mfma_f32_16x16x32_bf16(kf, qf, zero, 0, 0, 0);
                // C-layout: col=query=lane&15, row=key=quad*4+reg
                float p0 = __expf(sc[0]), p1 = __expf(sc[1]);
                float p2 = __expf(sc[2]), p3 = __expf(sc[3]);
                l += (p0 + p1) + (p2 + p3);
                uint2 pk;                           // packed v_cvt_pk_bf16_f32 (RNE)
                pk.x = pk2bf(p0, p1);
                pk.y = pk2bf(p2, p3);
                *(uint2*)&Pw[q15 * 40 + t * 16 + quad * 4] = pk;
            }
            asm volatile("s_waitcnt lgkmcnt(0)" ::: "memory");
            short8 pf = *(const short8*)&Pw[q15 * 40 + quad * 8];        // A: m=query, k=key
            short8 vf = *(const short8*)&Vsh[q15 * 80 + t2 * 32 + quad * 8];  // B: n=dh, k=key
            O = __builtin_amdgcn_mfma_f32_16x16x32_bf16(pf, vf, O, 0, 0, 0);
        }
    }

    l += __shfl_xor(l, 16);
    l += __shfl_xor(l, 32);
    if (lane < 16)
        lpart[((size_t)h * N + qbase + q15) * NSPLIT + sp] = l;
#pragma unroll
    for (int r = 0; r < 4; ++r) {
        int query = qbase + quad * 4 + r;
        opart[(((size_t)h * N + query) * NSPLIT + sp) * 16 + q15] = O[r];
    }
}

// ===== D4b: combine splits -> Wout gemm (+b_out) -> W2 gemm -> h2pre =====
__global__ __launch_bounds__(256) void d4b_kernel(const float* __restrict__ Wout,
        const float* __restrict__ b_out, const float* __restrict__ W2,
        float* __restrict__ ws) {
    __shared__ float4 WoS[64 * 17];    // 17408
    __shared__ float4 W2S[96 * 17];    // 26112 (86 used)
    __shared__ float  o_sh[16 * 68];   // 4352
    __shared__ float  Bf[16 * 68];     // 4352

    const float* opart = ws + OFF_OPART;
    const float* lpart = ws + OFF_LPART;
    float* h2pre = ws + OFF_H2;

    const int tid = threadIdx.x, qbase = blockIdx.x * 16;
    for (int idx = tid; idx < 64 * 16; idx += 256)
        WoS[(idx >> 4) * 17 + (idx & 15)] = ((const float4*)Wout)[idx];
    for (int idx = tid; idx < 86 * 16; idx += 256)
        W2S[(idx >> 4) * 17 + (idx & 15)] = ((const float4*)W2)[idx];

    // combine: o_sh[r][f] = sum_s opart / sum_s lpart
    for (int idx = tid; idx < 16 * 64; idx += 256) {
        int r = idx >> 6, f = idx & 63;
        int h = f >> 4, d = f & 15;
        size_t base = ((size_t)h * N + qbase + r) * NSPLIT;
        float L = 0.f, acc = 0.f;
#pragma unroll
        for (int s = 0; s < NSPLIT; ++s) {
            L += lpart[base + s];
            acc += opart[(base + s) * 16 + d];
        }
        o_sh[r * 68 + f] = acc / L;
    }
    __syncthreads();
    // Wout gemm: 16 rows x 64 cols
    {
        int r = tid & 15, c0 = tid >> 4;
        float4* o4 = (float4*)o_sh;
#pragma unroll
        for (int i = 0; i < 4; ++i) {
            int c = c0 + 16 * i;
            float acc = b_out[c];
#pragma unroll
            for (int k4 = 0; k4 < 16; ++k4) {
                float4 a = o4[r * 17 + k4];
                float4 w = WoS[c * 17 + k4];
                acc += a.x * w.x + a.y * w.y + a.z * w.z + a.w * w.w;
            }
            Bf[r * 68 + c] = acc;
        }
    }
    __syncthreads();
    // W2 gemm: 16 rows x 86 cols -> h2pre
    {
        int r = tid & 15, c0 = tid >> 4;
        float4* B4 = (float4*)Bf;
#pragma unroll
        for (int i = 0; i < 6; ++i) {
            int c = c0 + 16 * i;
            if (c < OUTF) {
                float acc = 0.f;
#pragma unroll
                for (int k4 = 0; k4 < 16; ++k4) {
                    float4 a = B4[r * 17 + k4];
                    float4 w = W2S[c * 17 + k4];
                    acc += a.x * w.x + a.y * w.y + a.z * w.z + a.w * w.w;
                }
                h2pre[(size_t)(qbase + r) * OUTF + c] = acc;
            }
        }
    }
}

// ===== D5: agg2 + LDS per-graph pre-reduction + few atomics into out =====
__global__ __launch_bounds__(1024) void d5_kernel(const int* __restrict__ batch,
        float* __restrict__ ws, float* __restrict__ out) {
    __shared__ float vec[16][88];
    __shared__ int   bix[16];

    const unsigned long long* pck = (const unsigned long long*)(ws + OFF_PCK);
    const int2*  epair = (const int2*)(ws + OFF_EPAIR);
    const float* normv = ws + OFF_NORMV;   // norms (written by D23)
    const float* invcnt= ws + OFF_INV;
    const float* h2pre = ws + OFF_H2;

    const int tid = threadIdx.x;
    const int lane = tid & 63, wv = tid >> 6;        // wv in [0,16)
    const int node = blockIdx.x * 16 + wv;
    const bool hi2 = lane < (OUTF - 64);
    const int b = batch[node];
    const float inv = invcnt[b];
    const unsigned long long pkn = pck[(size_t)node * PCKS];
    const float di2 = 1.0f / (pk_deg(pkn) + 1.0f);
    const float* Hn = h2pre + (size_t)node * OUTF;
    float a0 = di2 * Hn[lane],                  a1 = 0.f, a2 = 0.f, a3 = 0.f;
    float c0 = hi2 ? di2 * Hn[64 + lane] : 0.f, c1 = 0.f, c2 = 0.f, c3 = 0.f;
    const int cnt = min((int)(pkn >> 40), CAP);
    const int2* pe = epair + (size_t)node * CAP;

    for (int base = 0; base < cnt; base += 64) {
        int rem = cnt - base;
        int   sl = 0;
        float nl = 0.f;
        if (lane < rem) {
            sl = pe[base + lane].x;
            nl = normv[(size_t)node * CAP + base + lane];
        }
        int m = rem < 64 ? rem : 64;
        int j = 0;
        for (; j + 8 <= m; j += 8) {               // 8 rows (16 loads) in flight
            int   s0 = __shfl(sl, j),     s1 = __shfl(sl, j + 1);
            int   s2 = __shfl(sl, j + 2), s3 = __shfl(sl, j + 3);
            int   s4 = __shfl(sl, j + 4), s5 = __shfl(sl, j + 5);
            int   s6 = __shfl(sl, j + 6), s7 = __shfl(sl, j + 7);
            float n0 = __shfl(nl, j),     n1 = __shfl(nl, j + 1);
            float n2 = __shfl(nl, j + 2), n3 = __shfl(nl, j + 3);
            float n4 = __shfl(nl, j + 4), n5 = __shfl(nl, j + 5);
            float n6 = __shfl(nl, j + 6), n7 = __shfl(nl, j + 7);
            const float* H0 = h2pre + (size_t)s0 * OUTF;
            const float* H1 = h2pre + (size_t)s1 * OUTF;
            const float* H2 = h2pre + (size_t)s2 * OUTF;
            const float* H3 = h2pre + (size_t)s3 * OUTF;
            const float* H4 = h2pre + (size_t)s4 * OUTF;
            const float* H5 = h2pre + (size_t)s5 * OUTF;
            const float* H6 = h2pre + (size_t)s6 * OUTF;
            const float* H7 = h2pre + (size_t)s7 * OUTF;
            float v0 = H0[lane], v1 = H1[lane], v2 = H2[lane], v3 = H3[lane];
            float v4 = H4[lane], v5 = H5[lane], v6 = H6[lane], v7 = H7[lane];
            a0 += n0 * v0; a1 += n1 * v1; a2 += n2 * v2; a3 += n3 * v3;
            a0 += n4 * v4; a1 += n5 * v5; a2 += n6 * v6; a3 += n7 * v7;
            if (hi2) {
                float w0 = H0[64 + lane], w1 = H1[64 + lane];
                float w2 = H2[64 + lane], w3 = H3[64 + lane];
                float w4 = H4[64 + lane], w5 = H5[64 + lane];
                float w6 = H6[64 + lane], w7 = H7[64 + lane];
                c0 += n0 * w0; c1 += n1 * w1; c2 += n2 * w2; c3 += n3 * w3;
                c0 += n4 * w4; c1 += n5 * w5; c2 += n6 * w6; c3 += n7 * w7;
            }
        }
        for (; j + 4 <= m; j += 4) {
            int   s0 = __shfl(sl, j),     s1 = __shfl(sl, j + 1);
            int   s2 = __shfl(sl, j + 2), s3 = __shfl(sl, j + 3);
            float n0 = __shfl(nl, j),     n1 = __shfl(nl, j + 1);
            float n2 = __shfl(nl, j + 2), n3 = __shfl(nl, j + 3);
            const float* H0 = h2pre + (size_t)s0 * OUTF;
            const float* H1 = h2pre + (size_t)s1 * OUTF;
            const float* H2 = h2pre + (size_t)s2 * OUTF;
            const float* H3 = h2pre + (size_t)s3 * OUTF;
            a0 += n0 * H0[lane]; if (hi2) c0 += n0 * H0[64 + lane];
            a1 += n1 * H1[lane]; if (hi2) c1 += n1 * H1[64 + lane];
            a2 += n2 * H2[lane]; if (hi2) c2 += n2 * H2[64 + lane];
            a3 += n3 * H3[lane]; if (hi2) c3 += n3 * H3[64 + lane];
        }
        for (; j < m; ++j) {
            int   s0 = __shfl(sl, j);
            float n0 = __shfl(nl, j);
            const float* H0 = h2pre + (size_t)s0 * OUTF;
            a0 += n0 * H0[lane];
            if (hi2) c0 += n0 * H0[64 + lane];
        }
    }
    vec[wv][lane] = ((a0 + a1) + (a2 + a3)) * inv;
    if (hi2) vec[wv][64 + lane] = ((c0 + c1) + (c2 + c3)) * inv;
    if (lane == 0) bix[wv] = b;
    __syncthreads();
    // per-graph pre-reduction over the 16 sorted nodes: 1 atomic per (graph, feat) per block
    if (tid < OUTF) {
        int curb = bix[0];
        float acc = 0.f;
#pragma unroll
        for (int w = 0; w < 16; ++w) {
            int bw = bix[w];
            if (bw != curb) {
                atomicAdd(&out[curb * OUTF + tid], acc);
                curb = bw; acc = 0.f;
            }
            acc += vec[w][tid];
        }
        atomicAdd(&out[curb * OUTF + tid], acc);
    }
}

extern "C" void kernel_launch(void* const* d_in, const int* in_sizes, int n_in,
                              void* d_out, int out_size, void* d_ws, size_t ws_size,
                              hipStream_t stream) {
    const float* x     = (const float*)d_in[0];
    const int*   ei    = (const int*)  d_in[1];
    const float* ea    = (const float*)d_in[2];
    const int*   batch = (const int*)  d_in[3];
    const float* W1    = (const float*)d_in[4];
    const float* b1    = (const float*)d_in[5];
    const float* Win   = (const float*)d_in[6];
    const float* b_in  = (const float*)d_in[7];
    const float* Wout  = (const float*)d_in[8];
    const float* b_out = (const float*)d_in[9];
    const float* W2    = (const float*)d_in[10];
    const float* b2    = (const float*)d_in[11];
    float* out = (float*)d_out;
    float* ws  = (float*)d_ws;

    // zero padded pck array (N lines of 64 B)
    hipMemsetAsync(ws + OFF_PCK, 0, (size_t)N * 64, stream);
    d1_kernel<<<513, 256, 0, stream>>>(x, W1, ei, ea, batch, b2, ws, out);
    d23_kernel<<<N / 16, 1024, 0, stream>>>(Win, b1, b_in, ws);
    attn_kernel<<<dim3(N / 256, HEADS, NSPLIT), 1024, 0, stream>>>(ws, ws);
    d4b_kernel<<<N / 16, 256, 0, stream>>>(Wout, b_out, W2, ws);
    d5_kernel<<<N / 16, 1024, 0, stream>>>(batch, ws, out);
}

// Round 7
// 138.980 us; speedup vs baseline: 2.1241x; 1.0704x over previous
//
#include <hip/hip_runtime.h>
#include <hip/hip_bf16.h>

// Problem constants
constexpr int N = 4096, E = 131072, OUTF = 86, NB = 16, HEADS = 4, DH = 16;
constexpr int CAP = 128;   // padded bucket capacity per node (mean deg = 32)
constexpr int NSPLIT = 4, KEYS = N / NSPLIT;  // 1024 keys per attention split
constexpr int PCKS = 8;    // u64 stride per node in pck (64 B line per node)

typedef __attribute__((ext_vector_type(8))) short short8;
typedef __attribute__((ext_vector_type(4))) float f32x4;

constexpr unsigned long long PK_MASK = (1ULL << 40) - 1;  // low 40: fixed-point deg
constexpr float PK_SCALE = 1.0f / 16777216.0f;            // 2^-24
constexpr float QSCALE = 0.25f * 1.44269504088896340736f; // 1/sqrt(DH) * log2(e)

// Workspace offsets (float units, 16B-aligned)
constexpr size_t OFF_PCK   = 0;                           // N*PCKS u64 = 16N words
constexpr size_t OFF_INV   = OFF_PCK + 16 * (size_t)N;    // 16
constexpr size_t OFF_BUFA  = OFF_INV + 16;                // N*64 (xW1)
constexpr size_t OFF_QP    = OFF_BUFA + (size_t)N * 64;   // HEADS*N*16 bf16 = N*32 floats
constexpr size_t OFF_KP    = OFF_QP + (size_t)N * 32;
constexpr size_t OFF_VP    = OFF_KP + (size_t)N * 32;     // [h][16][N] bf16
constexpr size_t OFF_H2    = OFF_VP + (size_t)N * 32;     // N*86 (h2pre)
constexpr size_t OFF_EPAIR = OFF_H2 + (size_t)N * 86;     // N*CAP int2 {src, w}
constexpr size_t OFF_NORMV = OFF_EPAIR + (size_t)2 * N * CAP;  // N*CAP floats
constexpr size_t OFF_OPART = OFF_NORMV + (size_t)N * CAP; // HEADS*N*NSPLIT*16
constexpr size_t OFF_LPART = OFF_OPART + (size_t)HEADS * N * NSPLIT * 16;  // HEADS*N*NSPLIT

__device__ inline unsigned short f2bf(float f) {  // RNE float->bf16
    unsigned u = __builtin_bit_cast(unsigned, f);
    u += 0x7FFFu + ((u >> 16) & 1u);
    return (unsigned short)(u >> 16);
}

__device__ inline unsigned pk2bf(float a, float b) {  // packed RNE pair
    __hip_bfloat162 h2 = __float22bfloat162_rn(make_float2(a, b));
    union { __hip_bfloat162 h; unsigned u; } c;
    c.h = h2;
    return c.u;
}

__device__ inline float pk_deg(unsigned long long pk) {   // decode weighted degree
    return (float)(pk & PK_MASK) * PK_SCALE;
}

// ===== D1: gemm1 (blk<256) || edge bucket fill x2 (256..511) || out-init (512) =====
__global__ __launch_bounds__(256) void d1_kernel(const float* __restrict__ x,
        const float* __restrict__ W1, const int* __restrict__ ei,
        const float* __restrict__ ea, const int* __restrict__ batch,
        const float* __restrict__ b2, float* __restrict__ ws, float* __restrict__ out) {
    __shared__ float4 Ws4[64 * 17];
    __shared__ float4 As4[16 * 17];
    __shared__ int bnd[NB + 1];
    int blk = blockIdx.x, tid = threadIdx.x;
    if (blk < 256) {
        float* bufA = ws + OFF_BUFA;
        for (int idx = tid; idx < 64 * 16; idx += 256)
            Ws4[(idx >> 4) * 17 + (idx & 15)] = ((const float4*)W1)[idx];
        {
            int r = tid >> 4, k4 = tid & 15;
            As4[r * 17 + k4] = ((const float4*)x)[(size_t)(blk * 16 + r) * 16 + k4];
        }
        __syncthreads();
        int r2 = tid & 7, cg = tid >> 3;
        float acc[2][2] = {};
#pragma unroll
        for (int k4 = 0; k4 < 16; ++k4) {
            float4 a0 = As4[r2 * 17 + k4], a1 = As4[(r2 + 8) * 17 + k4];
#pragma unroll
            for (int i = 0; i < 2; ++i) {
                float4 w = Ws4[(cg + 32 * i) * 17 + k4];
                acc[0][i] += a0.x * w.x + a0.y * w.y + a0.z * w.z + a0.w * w.w;
                acc[1][i] += a1.x * w.x + a1.y * w.y + a1.z * w.z + a1.w * w.w;
            }
        }
#pragma unroll
        for (int j = 0; j < 2; ++j)
#pragma unroll
            for (int i = 0; i < 2; ++i)
                bufA[(size_t)(blk * 16 + r2 + 8 * j) * 64 + cg + 32 * i] = acc[j][i];
    } else if (blk < 512) {
        unsigned long long* pck = (unsigned long long*)(ws + OFF_PCK);
        int2* epair = (int2*)(ws + OFF_EPAIR);
        int f = (blk - 256) * 256 + tid;          // [0, E/2)
        int e0 = f, e1 = f + E / 2;
        int s0 = ei[e0], d0 = ei[E + e0];
        int s1 = ei[e1], d1 = ei[E + e1];
        float w0 = ea[e0], w1 = ea[e1];
        unsigned long long a0 = (1ULL << 40) + (unsigned long long)(unsigned)(w0 * 16777216.0f + 0.5f);
        unsigned long long a1 = (1ULL << 40) + (unsigned long long)(unsigned)(w1 * 16777216.0f + 0.5f);
        unsigned long long o0 = atomicAdd(&pck[(size_t)d0 * PCKS], a0);
        unsigned long long o1 = atomicAdd(&pck[(size_t)d1 * PCKS], a1);
        int p0 = (int)(o0 >> 40), p1 = (int)(o1 >> 40);
        if (p0 < CAP) epair[(size_t)d0 * CAP + p0] = make_int2(s0, __float_as_int(w0));
        if (p1 < CAP) epair[(size_t)d1 * CAP + p1] = make_int2(s1, __float_as_int(w1));
    } else {
        // out-init: 17 PARALLEL binary searches (one per graph boundary), then broadcast
        float* invcnt = ws + OFF_INV;
        if (tid <= NB) {
            int b = tid, lo = 0, hi = N;
            while (lo < hi) { int m = (lo + hi) >> 1; if (batch[m] < b) lo = m + 1; else hi = m; }
            bnd[tid] = lo;
        }
        __syncthreads();
        if (tid < NB) {
            int cnt = bnd[tid + 1] - bnd[tid];
            invcnt[tid] = cnt > 0 ? 1.0f / (float)cnt : 0.0f;
        }
        for (int idx = tid; idx < NB * OUTF; idx += 256) {
            int b = idx / OUTF;
            int cnt = bnd[b + 1] - bnd[b];
            out[idx] = cnt > 0 ? b2[idx - b * OUTF] : 0.0f;
        }
    }
}

// ===== D23: fused agg1(+b1,ReLU in LDS) -> QKV gemm + bf16 pack =====
// Gather inner loop: LDS edge staging + uniform-address broadcast ds_read_b64
// (replaces 2x ds_bpermute per edge -> ~half the DS-pipe issue traffic).
__global__ __launch_bounds__(1024) void d23_kernel(const float* __restrict__ Win,
        const float* __restrict__ b1, const float* __restrict__ b_in,
        float* __restrict__ ws) {
    __shared__ float4 Ws4[16 * 200];   // [k4][c] (c<192, pad 200): 51200 B
    __shared__ float  Af[16 * 68];     // 4352 B
    __shared__ int2   Ed[16][64];      // 8192 B (per-wave edge stage) -> total 63744 B

    const unsigned long long* pck = (const unsigned long long*)(ws + OFF_PCK);
    const int2*  epair = (const int2*)(ws + OFF_EPAIR);
    float*       normv = ws + OFF_NORMV;
    const float* bufA  = ws + OFF_BUFA;
    unsigned short* Qp = (unsigned short*)(ws + OFF_QP);
    unsigned short* Kp = (unsigned short*)(ws + OFF_KP);
    unsigned short* Vp = (unsigned short*)(ws + OFF_VP);

    const int tid = threadIdx.x, lane = tid & 63, wv = tid >> 6;
    for (int idx = tid; idx < 192 * 16; idx += 1024) {
        int c = idx >> 4, k4 = idx & 15;
        Ws4[k4 * 200 + c] = ((const float4*)Win)[idx];
    }

    // phase 1: wave wv aggregates node
    const int node = blockIdx.x * 16 + wv;
    {
        const unsigned long long pkn = pck[(size_t)node * PCKS];
        const float di = rsqrtf(pk_deg(pkn) + 1.0f);   // self-loop: deg+1
        float acc0 = (di * di) * bufA[(size_t)node * 64 + lane];
        float acc1 = 0.f, acc2 = 0.f, acc3 = 0.f;
        const int cnt = min((int)(pkn >> 40), CAP);
        const int2* pe = epair + (size_t)node * CAP;
        for (int base = 0; base < cnt; base += 64) {
            int rem = cnt - base;
            int   sl = 0;
            float nl = 0.f;
            if (lane < rem) {                      // coalesced 8B load per lane
                int2 e = pe[base + lane];
                sl = e.x;
                float w = __int_as_float(e.y);
                nl = rsqrtf(pk_deg(pck[(size_t)sl * PCKS]) + 1.0f) * w * di;
                normv[(size_t)node * CAP + base + lane] = nl;   // for D5
            }
            Ed[wv][lane] = make_int2(sl, __float_as_int(nl));   // wave-private stage
            int m = rem < 64 ? rem : 64;
            int j = 0;
            for (; j + 8 <= m; j += 8) {           // 8 row-gathers in flight
                int2 e0 = Ed[wv][j],     e1 = Ed[wv][j + 1];    // uniform-addr broadcast
                int2 e2 = Ed[wv][j + 2], e3 = Ed[wv][j + 3];
                int2 e4 = Ed[wv][j + 4], e5 = Ed[wv][j + 5];
                int2 e6 = Ed[wv][j + 6], e7 = Ed[wv][j + 7];
                float v0 = bufA[(size_t)e0.x * 64 + lane], v1 = bufA[(size_t)e1.x * 64 + lane];
                float v2 = bufA[(size_t)e2.x * 64 + lane], v3 = bufA[(size_t)e3.x * 64 + lane];
                float v4 = bufA[(size_t)e4.x * 64 + lane], v5 = bufA[(size_t)e5.x * 64 + lane];
                float v6 = bufA[(size_t)e6.x * 64 + lane], v7 = bufA[(size_t)e7.x * 64 + lane];
                acc0 += __int_as_float(e0.y) * v0; acc1 += __int_as_float(e1.y) * v1;
                acc2 += __int_as_float(e2.y) * v2; acc3 += __int_as_float(e3.y) * v3;
                acc0 += __int_as_float(e4.y) * v4; acc1 += __int_as_float(e5.y) * v5;
                acc2 += __int_as_float(e6.y) * v6; acc3 += __int_as_float(e7.y) * v7;
            }
            for (; j < m; ++j) {
                int2 e0 = Ed[wv][j];
                acc0 += __int_as_float(e0.y) * bufA[(size_t)e0.x * 64 + lane];
            }
        }
        Af[wv * 68 + lane] = fmaxf((acc0 + acc1) + (acc2 + acc3) + b1[lane], 0.0f);
    }
    __syncthreads();

    // phase 2: wave wv computes QKV row (node); lane handles cols {lane, lane+64, lane+128}
    {
        const float4* Af4 = (const float4*)Af;
        float acc[3];
#pragma unroll
        for (int i = 0; i < 3; ++i) acc[i] = b_in[lane + 64 * i];
#pragma unroll
        for (int k4 = 0; k4 < 16; ++k4) {
            float4 a = Af4[wv * 17 + k4];          // wave-broadcast
#pragma unroll
            for (int i = 0; i < 3; ++i) {
                float4 w = Ws4[k4 * 200 + lane + 64 * i];  // lane-consecutive
                acc[i] += a.x * w.x + a.y * w.y + a.z * w.z + a.w * w.w;
            }
        }
        const int row = node;
#pragma unroll
        for (int i = 0; i < 3; ++i) {
            int c = lane + 64 * i;
            float v = acc[i];
            if (c < 64) {
                int h = c >> 4, d = c & 15;
                Qp[((size_t)h * N + row) * 16 + d] = f2bf(v * QSCALE);  // folds log2(e)
            } else if (c < 128) {
                int c2 = c - 64, h = c2 >> 4, d = c2 & 15;
                Kp[((size_t)h * N + row) * 16 + d] = f2bf(v);
            } else {
                int c2 = c - 128, h = c2 >> 4, d = c2 & 15;
                Vp[((size_t)h * 16 + d) * N + row] = f2bf(v);
            }
        }
    }
}

// ===== attn: MFMA flash attention, KV-split, double-buffered block-shared K/V =====
// 1024-thread blocks = 16 waves = 16 q-tiles sharing one (h, sp) K/V stream.
// Double-buffer: issue next-slab global loads into regs BEFORE computing current
// slab; write regs->LDS after compute; ONE barrier per slab (was 2) and the
// global-load latency hides under MFMA+exp (T14 pattern).
__global__ __launch_bounds__(1024) void attn_kernel(const float* __restrict__ ws_c,
        float* __restrict__ ws) {
    __shared__ __align__(16) unsigned short Ksh[2][64 * 24];  // [key][dh], 48 B rows
    __shared__ __align__(16) unsigned short Vsh[2][16 * 80];  // [dh][key], 160 B rows
    __shared__ __align__(16) unsigned short Plds[16 * 640];   // per-wave P roundtrip

    const unsigned short* Qp = (const unsigned short*)(ws_c + OFF_QP);
    const unsigned short* Kp = (const unsigned short*)(ws_c + OFF_KP);
    const unsigned short* Vp = (const unsigned short*)(ws_c + OFF_VP);
    float* opart = ws + OFF_OPART;
    float* lpart = ws + OFF_LPART;

    const int h  = blockIdx.y;
    const int sp = blockIdx.z;
    const int k0 = sp * KEYS;
    const int tid = threadIdx.x;
    const int lane = tid & 63, wv = tid >> 6;
    const int q15 = lane & 15, quad = lane >> 4;

    const int qbase = blockIdx.x * 256 + wv * 16;
    short8 qf = {};
    if (quad < 2)
        qf = *(const short8*)&Qp[((size_t)h * N + qbase + q15) * 16 + quad * 8];

    f32x4 O = {0.f, 0.f, 0.f, 0.f};
    float l = 0.f;
    unsigned short* Pw = &Plds[wv * 640];
    const unsigned short* Kh = Kp + (size_t)h * N * 16;
    const unsigned short* Vh = Vp + (size_t)h * 16 * N;

    // staging index precompute
    const int krow = tid >> 3, kp = tid & 7;       // K: threads 0..511, 8 per 16-dh key row
    const int vd = tid >> 6, vk = tid & 63;        // V: 64 threads per dh row

    // prologue: stage slab 0
    short2 kr = {};
    unsigned short vr;
    if (tid < 512)
        kr = *(const short2*)&Kh[(size_t)(k0 + krow) * 16 + kp * 2];
    vr = Vh[(size_t)vd * N + k0 + vk];
    if (tid < 512)
        *(short2*)&Ksh[0][krow * 24 + kp * 2] = kr;
    Vsh[0][vd * 80 + vk] = vr;
    __syncthreads();

    int cur = 0;
    for (int s = 0; s < KEYS / 64; ++s) {          // 16 slabs of 64 keys
        const bool hasnext = (s + 1 < KEYS / 64);
        if (hasnext) {                             // issue next-slab loads early
            if (tid < 512)
                kr = *(const short2*)&Kh[(size_t)(k0 + (s + 1) * 64 + krow) * 16 + kp * 2];
            vr = Vh[(size_t)vd * N + k0 + (s + 1) * 64 + vk];
        }
        const unsigned short* Kc = Ksh[cur];
        const unsigned short* Vc = Vsh[cur];
#pragma unroll
        for (int t2 = 0; t2 < 2; ++t2) {           // two 32-key chunks per slab
#pragma unroll
            for (int t = 0; t < 2; ++t) {
                short8 kf = {};
                if (quad < 2)
                    kf = *(const short8*)&Kc[(t2 * 32 + t * 16 + q15) * 24 + quad * 8];
                f32x4 zero = {0.f, 0.f, 0.f, 0.f};
                f32x4 sc = __builtin_amdgcn_mfma_f32_16x16x32_bf16(kf, qf, zero, 0, 0, 0);
                // C-layout: col=query=lane&15, row=key=quad*4+reg. Logits pre-scaled
                // by log2(e) at Q-pack -> native v_exp_f32 (2^x).
                float p0 = __builtin_amdgcn_exp2f(sc[0]), p1 = __builtin_amdgcn_exp2f(sc[1]);
                float p2 = __builtin_amdgcn_exp2f(sc[2]), p3 = __builtin_amdgcn_exp2f(sc[3]);
                l += (p0 + p1) + (p2 + p3);
                uint2 pk;                           // packed v_cvt_pk_bf16_f32 (RNE)
                pk.x = pk2bf(p0, p1);
                pk.y = pk2bf(p2, p3);
                *(uint2*)&Pw[q15 * 40 + t * 16 + quad * 4] = pk;
            }
            asm volatile("s_waitcnt lgkmcnt(0)" ::: "memory");
            short8 pf = *(const short8*)&Pw[q15 * 40 + quad * 8];        // A: m=query, k=key
            short8 vf = *(const short8*)&Vc[q15 * 80 + t2 * 32 + quad * 8];   // B: n=dh, k=key
            O = __builtin_amdgcn_mfma_f32_16x16x32_bf16(pf, vf, O, 0, 0, 0);
        }
        if (hasnext) {                             // write next slab after compute
            if (tid < 512)
                *(short2*)&Ksh[cur ^ 1][krow * 24 + kp * 2] = kr;
            Vsh[cur ^ 1][vd * 80 + vk] = vr;
        }
        __syncthreads();
        cur ^= 1;
    }

    l += __shfl_xor(l, 16);
    l += __shfl_xor(l, 32);
    if (lane < 16)
        lpart[((size_t)h * N + qbase + q15) * NSPLIT + sp] = l;
#pragma unroll
    for (int r = 0; r < 4; ++r) {
        int query = qbase + quad * 4 + r;
        opart[(((size_t)h * N + query) * NSPLIT + sp) * 16 + q15] = O[r];
    }
}

// ===== D4b: combine splits -> Wout gemm (+b_out) -> W2 gemm -> h2pre =====
__global__ __launch_bounds__(256) void d4b_kernel(const float* __restrict__ Wout,
        const float* __restrict__ b_out, const float* __restrict__ W2,
        float* __restrict__ ws) {
    __shared__ float4 WoS[64 * 17];    // 17408
    __shared__ float4 W2S[96 * 17];    // 26112 (86 used)
    __shared__ float  o_sh[16 * 68];   // 4352
    __shared__ float  Bf[16 * 68];     // 4352

    const float* opart = ws + OFF_OPART;
    const float* lpart = ws + OFF_LPART;
    float* h2pre = ws + OFF_H2;

    const int tid = threadIdx.x, qbase = blockIdx.x * 16;
    for (int idx = tid; idx < 64 * 16; idx += 256)
        WoS[(idx >> 4) * 17 + (idx & 15)] = ((const float4*)Wout)[idx];
    for (int idx = tid; idx < 86 * 16; idx += 256)
        W2S[(idx >> 4) * 17 + (idx & 15)] = ((const float4*)W2)[idx];

    // combine: o_sh[r][f] = sum_s opart / sum_s lpart
    for (int idx = tid; idx < 16 * 64; idx += 256) {
        int r = idx >> 6, f = idx & 63;
        int h = f >> 4, d = f & 15;
        size_t base = ((size_t)h * N + qbase + r) * NSPLIT;
        float L = 0.f, acc = 0.f;
#pragma unroll
        for (int s = 0; s < NSPLIT; ++s) {
            L += lpart[base + s];
            acc += opart[(base + s) * 16 + d];
        }
        o_sh[r * 68 + f] = acc / L;
    }
    __syncthreads();
    // Wout gemm: 16 rows x 64 cols
    {
        int r = tid & 15, c0 = tid >> 4;
        float4* o4 = (float4*)o_sh;
#pragma unroll
        for (int i = 0; i < 4; ++i) {
            int c = c0 + 16 * i;
            float acc = b_out[c];
#pragma unroll
            for (int k4 = 0; k4 < 16; ++k4) {
                float4 a = o4[r * 17 + k4];
                float4 w = WoS[c * 17 + k4];
                acc += a.x * w.x + a.y * w.y + a.z * w.z + a.w * w.w;
            }
            Bf[r * 68 + c] = acc;
        }
    }
    __syncthreads();
    // W2 gemm: 16 rows x 86 cols -> h2pre
    {
        int r = tid & 15, c0 = tid >> 4;
        float4* B4 = (float4*)Bf;
#pragma unroll
        for (int i = 0; i < 6; ++i) {
            int c = c0 + 16 * i;
            if (c < OUTF) {
                float acc = 0.f;
#pragma unroll
                for (int k4 = 0; k4 < 16; ++k4) {
                    float4 a = B4[r * 17 + k4];
                    float4 w = W2S[c * 17 + k4];
                    acc += a.x * w.x + a.y * w.y + a.z * w.z + a.w * w.w;
                }
                h2pre[(size_t)(qbase + r) * OUTF + c] = acc;
            }
        }
    }
}

// ===== D5: agg2 + LDS per-graph pre-reduction + few atomics into out =====
// Gather inner loop: LDS edge staging + broadcast reads (as in D23).
__global__ __launch_bounds__(1024) void d5_kernel(const int* __restrict__ batch,
        float* __restrict__ ws, float* __restrict__ out) {
    __shared__ float vec[16][88];
    __shared__ int   bix[16];
    __shared__ int2  Ed[16][64];       // 8 KB per-wave edge stage

    const unsigned long long* pck = (const unsigned long long*)(ws + OFF_PCK);
    const int2*  epair = (const int2*)(ws + OFF_EPAIR);
    const float* normv = ws + OFF_NORMV;   // norms (written by D23)
    const float* invcnt= ws + OFF_INV;
    const float* h2pre = ws + OFF_H2;

    const int tid = threadIdx.x;
    const int lane = tid & 63, wv = tid >> 6;        // wv in [0,16)
    const int node = blockIdx.x * 16 + wv;
    const bool hi2 = lane < (OUTF - 64);
    const int b = batch[node];
    const float inv = invcnt[b];
    const unsigned long long pkn = pck[(size_t)node * PCKS];
    const float di2 = 1.0f / (pk_deg(pkn) + 1.0f);
    const float* Hn = h2pre + (size_t)node * OUTF;
    float a0 = di2 * Hn[lane],                  a1 = 0.f, a2 = 0.f, a3 = 0.f;
    float c0 = hi2 ? di2 * Hn[64 + lane] : 0.f, c1 = 0.f, c2 = 0.f, c3 = 0.f;
    const int cnt = min((int)(pkn >> 40), CAP);
    const int2* pe = epair + (size_t)node * CAP;

    for (int base = 0; base < cnt; base += 64) {
        int rem = cnt - base;
        int   sl = 0;
        float nl = 0.f;
        if (lane < rem) {
            sl = pe[base + lane].x;
            nl = normv[(size_t)node * CAP + base + lane];
        }
        Ed[wv][lane] = make_int2(sl, __float_as_int(nl));
        int m = rem < 64 ? rem : 64;
        int j = 0;
        for (; j + 8 <= m; j += 8) {               // 8 rows (16 loads) in flight
            int2 e0 = Ed[wv][j],     e1 = Ed[wv][j + 1];
            int2 e2 = Ed[wv][j + 2], e3 = Ed[wv][j + 3];
            int2 e4 = Ed[wv][j + 4], e5 = Ed[wv][j + 5];
            int2 e6 = Ed[wv][j + 6], e7 = Ed[wv][j + 7];
            const float* H0 = h2pre + (size_t)e0.x * OUTF;
            const float* H1 = h2pre + (size_t)e1.x * OUTF;
            const float* H2 = h2pre + (size_t)e2.x * OUTF;
            const float* H3 = h2pre + (size_t)e3.x * OUTF;
            const float* H4 = h2pre + (size_t)e4.x * OUTF;
            const float* H5 = h2pre + (size_t)e5.x * OUTF;
            const float* H6 = h2pre + (size_t)e6.x * OUTF;
            const float* H7 = h2pre + (size_t)e7.x * OUTF;
            float n0 = __int_as_float(e0.y), n1 = __int_as_float(e1.y);
            float n2 = __int_as_float(e2.y), n3 = __int_as_float(e3.y);
            float n4 = __int_as_float(e4.y), n5 = __int_as_float(e5.y);
            float n6 = __int_as_float(e6.y), n7 = __int_as_float(e7.y);
            float v0 = H0[lane], v1 = H1[lane], v2 = H2[lane], v3 = H3[lane];
            float v4 = H4[lane], v5 = H5[lane], v6 = H6[lane], v7 = H7[lane];
            a0 += n0 * v0; a1 += n1 * v1; a2 += n2 * v2; a3 += n3 * v3;
            a0 += n4 * v4; a1 += n5 * v5; a2 += n6 * v6; a3 += n7 * v7;
            if (hi2) {
                float w0 = H0[64 + lane], w1 = H1[64 + lane];
                float w2 = H2[64 + lane], w3 = H3[64 + lane];
                float w4 = H4[64 + lane], w5 = H5[64 + lane];
                float w6 = H6[64 + lane], w7 = H7[64 + lane];
                c0 += n0 * w0; c1 += n1 * w1; c2 += n2 * w2; c3 += n3 * w3;
                c0 += n4 * w4; c1 += n5 * w5; c2 += n6 * w6; c3 += n7 * w7;
            }
        }
        for (; j < m; ++j) {
            int2 e0 = Ed[wv][j];
            const float* H0 = h2pre + (size_t)e0.x * OUTF;
            float n0 = __int_as_float(e0.y);
            a0 += n0 * H0[lane];
            if (hi2) c0 += n0 * H0[64 + lane];
        }
    }
    vec[wv][lane] = ((a0 + a1) + (a2 + a3)) * inv;
    if (hi2) vec[wv][64 + lane] = ((c0 + c1) + (c2 + c3)) * inv;
    if (lane == 0) bix[wv] = b;
    __syncthreads();
    // per-graph pre-reduction over the 16 sorted nodes: 1 atomic per (graph, feat) per block
    if (tid < OUTF) {
        int curb = bix[0];
        float acc = 0.f;
#pragma unroll
        for (int w = 0; w < 16; ++w) {
            int bw = bix[w];
            if (bw != curb) {
                atomicAdd(&out[curb * OUTF + tid], acc);
                curb = bw; acc = 0.f;
            }
            acc += vec[w][tid];
        }
        atomicAdd(&out[curb * OUTF + tid], acc);
    }
}

extern "C" void kernel_launch(void* const* d_in, const int* in_sizes, int n_in,
                              void* d_out, int out_size, void* d_ws, size_t ws_size,
                              hipStream_t stream) {
    const float* x     = (const float*)d_in[0];
    const int*   ei    = (const int*)  d_in[1];
    const float* ea    = (const float*)d_in[2];
    const int*   batch = (const int*)  d_in[3];
    const float* W1    = (const float*)d_in[4];
    const float* b1    = (const float*)d_in[5];
    const float* Win   = (const float*)d_in[6];
    const float* b_in  = (const float*)d_in[7];
    const float* Wout  = (const float*)d_in[8];
    const float* b_out = (const float*)d_in[9];
    const float* W2    = (const float*)d_in[10];
    const float* b2    = (const float*)d_in[11];
    float* out = (float*)d_out;
    float* ws  = (float*)d_ws;

    // zero padded pck array (N lines of 64 B)
    (void)hipMemsetAsync(ws + OFF_PCK, 0, (size_t)N * 64, stream);
    d1_kernel<<<513, 256, 0, stream>>>(x, W1, ei, ea, batch, b2, ws, out);
    d23_kernel<<<N / 16, 1024, 0, stream>>>(Win, b1, b_in, ws);
    attn_kernel<<<dim3(N / 256, HEADS, NSPLIT), 1024, 0, stream>>>(ws, ws);
    d4b_kernel<<<N / 16, 256, 0, stream>>>(Wout, b_out, W2, ws);
    d5_kernel<<<N / 16, 1024, 0, stream>>>(batch, ws, out);
}

// Round 8
// 137.987 us; speedup vs baseline: 2.1394x; 1.0072x over previous
//
#include <hip/hip_runtime.h>
#include <hip/hip_bf16.h>

// Problem constants
constexpr int N = 4096, E = 131072, OUTF = 86, NB = 16, HEADS = 4, DH = 16;
constexpr int CAP = 128;   // padded bucket capacity per node (mean deg = 32)
constexpr int NSPLIT = 4, KEYS = N / NSPLIT;  // 1024 keys per attention split
constexpr int PCKS = 8;    // u64 stride per node in pck (64 B line per node)

typedef __attribute__((ext_vector_type(8))) short short8;
typedef __attribute__((ext_vector_type(4))) float f32x4;

constexpr unsigned long long PK_MASK = (1ULL << 40) - 1;  // low 40: fixed-point deg
constexpr float PK_SCALE = 1.0f / 16777216.0f;            // 2^-24
constexpr float QSCALE = 0.25f * 1.44269504088896340736f; // 1/sqrt(DH) * log2(e)

// Workspace offsets (float units, 16B-aligned)
constexpr size_t OFF_PCK   = 0;                           // N*PCKS u64 = 16N words
constexpr size_t OFF_INV   = OFF_PCK + 16 * (size_t)N;    // 16
constexpr size_t OFF_BUFA  = OFF_INV + 16;                // N*64 (xW1)
constexpr size_t OFF_QP    = OFF_BUFA + (size_t)N * 64;   // HEADS*N*16 bf16 = N*32 floats
constexpr size_t OFF_KP    = OFF_QP + (size_t)N * 32;
constexpr size_t OFF_VP    = OFF_KP + (size_t)N * 32;     // [h][16][N] bf16
constexpr size_t OFF_H2    = OFF_VP + (size_t)N * 32;     // N*86 (h2pre)
constexpr size_t OFF_EPAIR = OFF_H2 + (size_t)N * 86;     // N*CAP int2 {src, w}
constexpr size_t OFF_NORMV = OFF_EPAIR + (size_t)2 * N * CAP;  // N*CAP floats
constexpr size_t OFF_OPART = OFF_NORMV + (size_t)N * CAP; // HEADS*N*NSPLIT*16
constexpr size_t OFF_LPART = OFF_OPART + (size_t)HEADS * N * NSPLIT * 16;  // HEADS*N*NSPLIT

__device__ inline unsigned short f2bf(float f) {  // RNE float->bf16
    unsigned u = __builtin_bit_cast(unsigned, f);
    u += 0x7FFFu + ((u >> 16) & 1u);
    return (unsigned short)(u >> 16);
}

__device__ inline unsigned pk2bf(float a, float b) {  // packed RNE pair
    __hip_bfloat162 h2 = __float22bfloat162_rn(make_float2(a, b));
    union { __hip_bfloat162 h; unsigned u; } c;
    c.h = h2;
    return c.u;
}

__device__ inline float pk_deg(unsigned long long pk) {   // decode weighted degree
    return (float)(pk & PK_MASK) * PK_SCALE;
}

// ===== D1: gemm1 (blk<256) || edge bucket fill x2 (256..511) || out-init (512) =====
__global__ __launch_bounds__(256) void d1_kernel(const float* __restrict__ x,
        const float* __restrict__ W1, const int* __restrict__ ei,
        const float* __restrict__ ea, const int* __restrict__ batch,
        const float* __restrict__ b2, float* __restrict__ ws, float* __restrict__ out) {
    __shared__ float4 Ws4[64 * 17];
    __shared__ float4 As4[16 * 17];
    __shared__ int bnd[NB + 1];
    int blk = blockIdx.x, tid = threadIdx.x;
    if (blk < 256) {
        float* bufA = ws + OFF_BUFA;
        for (int idx = tid; idx < 64 * 16; idx += 256)
            Ws4[(idx >> 4) * 17 + (idx & 15)] = ((const float4*)W1)[idx];
        {
            int r = tid >> 4, k4 = tid & 15;
            As4[r * 17 + k4] = ((const float4*)x)[(size_t)(blk * 16 + r) * 16 + k4];
        }
        __syncthreads();
        int r2 = tid & 7, cg = tid >> 3;
        float acc[2][2] = {};
#pragma unroll
        for (int k4 = 0; k4 < 16; ++k4) {
            float4 a0 = As4[r2 * 17 + k4], a1 = As4[(r2 + 8) * 17 + k4];
#pragma unroll
            for (int i = 0; i < 2; ++i) {
                float4 w = Ws4[(cg + 32 * i) * 17 + k4];
                acc[0][i] += a0.x * w.x + a0.y * w.y + a0.z * w.z + a0.w * w.w;
                acc[1][i] += a1.x * w.x + a1.y * w.y + a1.z * w.z + a1.w * w.w;
            }
        }
#pragma unroll
        for (int j = 0; j < 2; ++j)
#pragma unroll
            for (int i = 0; i < 2; ++i)
                bufA[(size_t)(blk * 16 + r2 + 8 * j) * 64 + cg + 32 * i] = acc[j][i];
    } else if (blk < 512) {
        unsigned long long* pck = (unsigned long long*)(ws + OFF_PCK);
        int2* epair = (int2*)(ws + OFF_EPAIR);
        int f = (blk - 256) * 256 + tid;          // [0, E/2)
        int e0 = f, e1 = f + E / 2;
        int s0 = ei[e0], d0 = ei[E + e0];
        int s1 = ei[e1], d1 = ei[E + e1];
        float w0 = ea[e0], w1 = ea[e1];
        unsigned long long a0 = (1ULL << 40) + (unsigned long long)(unsigned)(w0 * 16777216.0f + 0.5f);
        unsigned long long a1 = (1ULL << 40) + (unsigned long long)(unsigned)(w1 * 16777216.0f + 0.5f);
        unsigned long long o0 = atomicAdd(&pck[(size_t)d0 * PCKS], a0);
        unsigned long long o1 = atomicAdd(&pck[(size_t)d1 * PCKS], a1);
        int p0 = (int)(o0 >> 40), p1 = (int)(o1 >> 40);
        if (p0 < CAP) epair[(size_t)d0 * CAP + p0] = make_int2(s0, __float_as_int(w0));
        if (p1 < CAP) epair[(size_t)d1 * CAP + p1] = make_int2(s1, __float_as_int(w1));
    } else {
        // out-init: 17 PARALLEL binary searches (one per graph boundary), then broadcast
        float* invcnt = ws + OFF_INV;
        if (tid <= NB) {
            int b = tid, lo = 0, hi = N;
            while (lo < hi) { int m = (lo + hi) >> 1; if (batch[m] < b) lo = m + 1; else hi = m; }
            bnd[tid] = lo;
        }
        __syncthreads();
        if (tid < NB) {
            int cnt = bnd[tid + 1] - bnd[tid];
            invcnt[tid] = cnt > 0 ? 1.0f / (float)cnt : 0.0f;
        }
        for (int idx = tid; idx < NB * OUTF; idx += 256) {
            int b = idx / OUTF;
            int cnt = bnd[b + 1] - bnd[b];
            out[idx] = cnt > 0 ? b2[idx - b * OUTF] : 0.0f;
        }
    }
}

// ===== D23: fused agg1(+b1,ReLU in LDS) -> QKV gemm + bf16 pack =====
// Gather: 4-rows-per-instruction float4 layout. Lane = (row-group rg=lane>>4,
// col-quad c4=lane&15). One dwordx4 load covers 4 rows (1 KB/wave-instr);
// 64->16 VMEM instrs and 64->16 DS instrs per 64 edges. Rows beyond the valid
// count contribute 0 via Ed's zero padding (lanes >= rem wrote {0,0}).
__global__ __launch_bounds__(1024) void d23_kernel(const float* __restrict__ Win,
        const float* __restrict__ b1, const float* __restrict__ b_in,
        float* __restrict__ ws) {
    __shared__ float4 Ws4[16 * 200];   // [k4][c] (c<192, pad 200): 51200 B
    __shared__ float  Af[16 * 68];     // 4352 B
    __shared__ int2   Ed[16][64];      // 8192 B (per-wave edge stage) -> total 63744 B

    const unsigned long long* pck = (const unsigned long long*)(ws + OFF_PCK);
    const int2*  epair = (const int2*)(ws + OFF_EPAIR);
    float*       normv = ws + OFF_NORMV;
    const float* bufA  = ws + OFF_BUFA;
    const float4* bufA4 = (const float4*)(ws + OFF_BUFA);
    unsigned short* Qp = (unsigned short*)(ws + OFF_QP);
    unsigned short* Kp = (unsigned short*)(ws + OFF_KP);
    unsigned short* Vp = (unsigned short*)(ws + OFF_VP);

    const int tid = threadIdx.x, lane = tid & 63, wv = tid >> 6;
    for (int idx = tid; idx < 192 * 16; idx += 1024) {
        int c = idx >> 4, k4 = idx & 15;
        Ws4[k4 * 200 + c] = ((const float4*)Win)[idx];
    }

    // phase 1: wave wv aggregates node
    const int node = blockIdx.x * 16 + wv;
    {
        const int rg = lane >> 4, c4 = lane & 15;   // row-group, col-quad
        const unsigned long long pkn = pck[(size_t)node * PCKS];
        const float di = rsqrtf(pk_deg(pkn) + 1.0f);   // self-loop: deg+1
        float4 acc0 = {0.f, 0.f, 0.f, 0.f}, acc1 = acc0, acc2 = acc0, acc3 = acc0;
        if (rg == 0) {                               // self term only in group 0
            float4 sv = bufA4[(size_t)node * 16 + c4];
            float d2 = di * di;
            acc0.x = d2 * sv.x; acc0.y = d2 * sv.y; acc0.z = d2 * sv.z; acc0.w = d2 * sv.w;
        }
        const int cnt = min((int)(pkn >> 40), CAP);
        const int2* pe = epair + (size_t)node * CAP;
        for (int base = 0; base < cnt; base += 64) {
            int rem = cnt - base;
            int   sl = 0;
            float nl = 0.f;
            if (lane < rem) {                      // coalesced 8B load per lane
                int2 e = pe[base + lane];
                sl = e.x;
                float w = __int_as_float(e.y);
                nl = rsqrtf(pk_deg(pck[(size_t)sl * PCKS]) + 1.0f) * w * di;
                normv[(size_t)node * CAP + base + lane] = nl;   // for D5
            }
            Ed[wv][lane] = make_int2(sl, __float_as_int(nl));   // zero-pad beyond rem
            int m = rem < 64 ? rem : 64;
            for (int j = 0; j < m; j += 16) {       // 16 rows per step, 4 f4-loads in flight
                int2 e0 = Ed[wv][j + rg];           // 4-address broadcast reads
                int2 e1 = Ed[wv][j + 4 + rg];
                int2 e2 = Ed[wv][j + 8 + rg];
                int2 e3 = Ed[wv][j + 12 + rg];
                float4 v0 = bufA4[(size_t)e0.x * 16 + c4];
                float4 v1 = bufA4[(size_t)e1.x * 16 + c4];
                float4 v2 = bufA4[(size_t)e2.x * 16 + c4];
                float4 v3 = bufA4[(size_t)e3.x * 16 + c4];
                float n0 = __int_as_float(e0.y), n1 = __int_as_float(e1.y);
                float n2 = __int_as_float(e2.y), n3 = __int_as_float(e3.y);
                acc0.x += n0 * v0.x; acc0.y += n0 * v0.y; acc0.z += n0 * v0.z; acc0.w += n0 * v0.w;
                acc1.x += n1 * v1.x; acc1.y += n1 * v1.y; acc1.z += n1 * v1.z; acc1.w += n1 * v1.w;
                acc2.x += n2 * v2.x; acc2.y += n2 * v2.y; acc2.z += n2 * v2.z; acc2.w += n2 * v2.w;
                acc3.x += n3 * v3.x; acc3.y += n3 * v3.y; acc3.z += n3 * v3.z; acc3.w += n3 * v3.w;
            }
        }
        float4 acc;
        acc.x = (acc0.x + acc1.x) + (acc2.x + acc3.x);
        acc.y = (acc0.y + acc1.y) + (acc2.y + acc3.y);
        acc.z = (acc0.z + acc1.z) + (acc2.z + acc3.z);
        acc.w = (acc0.w + acc1.w) + (acc2.w + acc3.w);
        // fold the 4 row-groups (lanes l, l+16, l+32, l+48 share a col-quad)
        acc.x += __shfl_xor(acc.x, 16); acc.y += __shfl_xor(acc.y, 16);
        acc.z += __shfl_xor(acc.z, 16); acc.w += __shfl_xor(acc.w, 16);
        acc.x += __shfl_xor(acc.x, 32); acc.y += __shfl_xor(acc.y, 32);
        acc.z += __shfl_xor(acc.z, 32); acc.w += __shfl_xor(acc.w, 32);
        if (rg == 0) {
            float4 b14 = ((const float4*)b1)[c4];
            float4 r;
            r.x = fmaxf(acc.x + b14.x, 0.f); r.y = fmaxf(acc.y + b14.y, 0.f);
            r.z = fmaxf(acc.z + b14.z, 0.f); r.w = fmaxf(acc.w + b14.w, 0.f);
            *(float4*)&Af[wv * 68 + c4 * 4] = r;    // byte offset wv*272+c4*16: aligned
        }
    }
    __syncthreads();

    // phase 2: wave wv computes QKV row (node); lane handles cols {lane, lane+64, lane+128}
    {
        const float4* Af4 = (const float4*)Af;
        float acc[3];
#pragma unroll
        for (int i = 0; i < 3; ++i) acc[i] = b_in[lane + 64 * i];
#pragma unroll
        for (int k4 = 0; k4 < 16; ++k4) {
            float4 a = Af4[wv * 17 + k4];          // wave-broadcast
#pragma unroll
            for (int i = 0; i < 3; ++i) {
                float4 w = Ws4[k4 * 200 + lane + 64 * i];  // lane-consecutive
                acc[i] += a.x * w.x + a.y * w.y + a.z * w.z + a.w * w.w;
            }
        }
        const int row = node;
#pragma unroll
        for (int i = 0; i < 3; ++i) {
            int c = lane + 64 * i;
            float v = acc[i];
            if (c < 64) {
                int h = c >> 4, d = c & 15;
                Qp[((size_t)h * N + row) * 16 + d] = f2bf(v * QSCALE);  // folds log2(e)
            } else if (c < 128) {
                int c2 = c - 64, h = c2 >> 4, d = c2 & 15;
                Kp[((size_t)h * N + row) * 16 + d] = f2bf(v);
            } else {
                int c2 = c - 128, h = c2 >> 4, d = c2 & 15;
                Vp[((size_t)h * 16 + d) * N + row] = f2bf(v);
            }
        }
    }
}

// ===== attn: MFMA flash attention, KV-split, double-buffered block-shared K/V =====
// 1024-thread blocks = 16 waves = 16 q-tiles sharing one (h, sp) K/V stream.
// Double-buffer: issue next-slab global loads into regs BEFORE computing current
// slab; write regs->LDS after compute; ONE barrier per slab (was 2) and the
// global-load latency hides under MFMA+exp (T14 pattern).
__global__ __launch_bounds__(1024) void attn_kernel(const float* __restrict__ ws_c,
        float* __restrict__ ws) {
    __shared__ __align__(16) unsigned short Ksh[2][64 * 24];  // [key][dh], 48 B rows
    __shared__ __align__(16) unsigned short Vsh[2][16 * 80];  // [dh][key], 160 B rows
    __shared__ __align__(16) unsigned short Plds[16 * 640];   // per-wave P roundtrip

    const unsigned short* Qp = (const unsigned short*)(ws_c + OFF_QP);
    const unsigned short* Kp = (const unsigned short*)(ws_c + OFF_KP);
    const unsigned short* Vp = (const unsigned short*)(ws_c + OFF_VP);
    float* opart = ws + OFF_OPART;
    float* lpart = ws + OFF_LPART;

    const int h  = blockIdx.y;
    const int sp = blockIdx.z;
    const int k0 = sp * KEYS;
    const int tid = threadIdx.x;
    const int lane = tid & 63, wv = tid >> 6;
    const int q15 = lane & 15, quad = lane >> 4;

    const int qbase = blockIdx.x * 256 + wv * 16;
    short8 qf = {};
    if (quad < 2)
        qf = *(const short8*)&Qp[((size_t)h * N + qbase + q15) * 16 + quad * 8];

    f32x4 O = {0.f, 0.f, 0.f, 0.f};
    float l = 0.f;
    unsigned short* Pw = &Plds[wv * 640];
    const unsigned short* Kh = Kp + (size_t)h * N * 16;
    const unsigned short* Vh = Vp + (size_t)h * 16 * N;

    // staging index precompute
    const int krow = tid >> 3, kp = tid & 7;       // K: threads 0..511, 8 per 16-dh key row
    const int vd = tid >> 6, vk = tid & 63;        // V: 64 threads per dh row

    // prologue: stage slab 0
    short2 kr = {};
    unsigned short vr;
    if (tid < 512)
        kr = *(const short2*)&Kh[(size_t)(k0 + krow) * 16 + kp * 2];
    vr = Vh[(size_t)vd * N + k0 + vk];
    if (tid < 512)
        *(short2*)&Ksh[0][krow * 24 + kp * 2] = kr;
    Vsh[0][vd * 80 + vk] = vr;
    __syncthreads();

    int cur = 0;
    for (int s = 0; s < KEYS / 64; ++s) {          // 16 slabs of 64 keys
        const bool hasnext = (s + 1 < KEYS / 64);
        if (hasnext) {                             // issue next-slab loads early
            if (tid < 512)
                kr = *(const short2*)&Kh[(size_t)(k0 + (s + 1) * 64 + krow) * 16 + kp * 2];
            vr = Vh[(size_t)vd * N + k0 + (s + 1) * 64 + vk];
        }
        const unsigned short* Kc = Ksh[cur];
        const unsigned short* Vc = Vsh[cur];
#pragma unroll
        for (int t2 = 0; t2 < 2; ++t2) {           // two 32-key chunks per slab
#pragma unroll
            for (int t = 0; t < 2; ++t) {
                short8 kf = {};
                if (quad < 2)
                    kf = *(const short8*)&Kc[(t2 * 32 + t * 16 + q15) * 24 + quad * 8];
                f32x4 zero = {0.f, 0.f, 0.f, 0.f};
                f32x4 sc = __builtin_amdgcn_mfma_f32_16x16x32_bf16(kf, qf, zero, 0, 0, 0);
                // C-layout: col=query=lane&15, row=key=quad*4+reg. Logits pre-scaled
                // by log2(e) at Q-pack -> native v_exp_f32 (2^x).
                float p0 = __builtin_amdgcn_exp2f(sc[0]), p1 = __builtin_amdgcn_exp2f(sc[1]);
                float p2 = __builtin_amdgcn_exp2f(sc[2]), p3 = __builtin_amdgcn_exp2f(sc[3]);
                l += (p0 + p1) + (p2 + p3);
                uint2 pk;                           // packed v_cvt_pk_bf16_f32 (RNE)
                pk.x = pk2bf(p0, p1);
                pk.y = pk2bf(p2, p3);
                *(uint2*)&Pw[q15 * 40 + t * 16 + quad * 4] = pk;
            }
            asm volatile("s_waitcnt lgkmcnt(0)" ::: "memory");
            short8 pf = *(const short8*)&Pw[q15 * 40 + quad * 8];        // A: m=query, k=key
            short8 vf = *(const short8*)&Vc[q15 * 80 + t2 * 32 + quad * 8];   // B: n=dh, k=key
            O = __builtin_amdgcn_mfma_f32_16x16x32_bf16(pf, vf, O, 0, 0, 0);
        }
        if (hasnext) {                             // write next slab after compute
            if (tid < 512)
                *(short2*)&Ksh[cur ^ 1][krow * 24 + kp * 2] = kr;
            Vsh[cur ^ 1][vd * 80 + vk] = vr;
        }
        __syncthreads();
        cur ^= 1;
    }

    l += __shfl_xor(l, 16);
    l += __shfl_xor(l, 32);
    if (lane < 16)
        lpart[((size_t)h * N + qbase + q15) * NSPLIT + sp] = l;
#pragma unroll
    for (int r = 0; r < 4; ++r) {
        int query = qbase + quad * 4 + r;
        opart[(((size_t)h * N + query) * NSPLIT + sp) * 16 + q15] = O[r];
    }
}

// ===== D4b: combine splits -> Wout gemm (+b_out) -> W2 gemm -> h2pre =====
__global__ __launch_bounds__(256) void d4b_kernel(const float* __restrict__ Wout,
        const float* __restrict__ b_out, const float* __restrict__ W2,
        float* __restrict__ ws) {
    __shared__ float4 WoS[64 * 17];    // 17408
    __shared__ float4 W2S[96 * 17];    // 26112 (86 used)
    __shared__ float  o_sh[16 * 68];   // 4352
    __shared__ float  Bf[16 * 68];     // 4352

    const float* opart = ws + OFF_OPART;
    const float* lpart = ws + OFF_LPART;
    float* h2pre = ws + OFF_H2;

    const int tid = threadIdx.x, qbase = blockIdx.x * 16;
    for (int idx = tid; idx < 64 * 16; idx += 256)
        WoS[(idx >> 4) * 17 + (idx & 15)] = ((const float4*)Wout)[idx];
    for (int idx = tid; idx < 86 * 16; idx += 256)
        W2S[(idx >> 4) * 17 + (idx & 15)] = ((const float4*)W2)[idx];

    // combine: o_sh[r][f] = sum_s opart / sum_s lpart
    for (int idx = tid; idx < 16 * 64; idx += 256) {
        int r = idx >> 6, f = idx & 63;
        int h = f >> 4, d = f & 15;
        size_t base = ((size_t)h * N + qbase + r) * NSPLIT;
        float L = 0.f, acc = 0.f;
#pragma unroll
        for (int s = 0; s < NSPLIT; ++s) {
            L += lpart[base + s];
            acc += opart[(base + s) * 16 + d];
        }
        o_sh[r * 68 + f] = acc / L;
    }
    __syncthreads();
    // Wout gemm: 16 rows x 64 cols
    {
        int r = tid & 15, c0 = tid >> 4;
        float4* o4 = (float4*)o_sh;
#pragma unroll
        for (int i = 0; i < 4; ++i) {
            int c = c0 + 16 * i;
            float acc = b_out[c];
#pragma unroll
            for (int k4 = 0; k4 < 16; ++k4) {
                float4 a = o4[r * 17 + k4];
                float4 w = WoS[c * 17 + k4];
                acc += a.x * w.x + a.y * w.y + a.z * w.z + a.w * w.w;
            }
            Bf[r * 68 + c] = acc;
        }
    }
    __syncthreads();
    // W2 gemm: 16 rows x 86 cols -> h2pre
    {
        int r = tid & 15, c0 = tid >> 4;
        float4* B4 = (float4*)Bf;
#pragma unroll
        for (int i = 0; i < 6; ++i) {
            int c = c0 + 16 * i;
            if (c < OUTF) {
                float acc = 0.f;
#pragma unroll
                for (int k4 = 0; k4 < 16; ++k4) {
                    float4 a = B4[r * 17 + k4];
                    float4 w = W2S[c * 17 + k4];
                    acc += a.x * w.x + a.y * w.y + a.z * w.z + a.w * w.w;
                }
                h2pre[(size_t)(qbase + r) * OUTF + c] = acc;
            }
        }
    }
}

// ===== D5: agg2 + LDS per-graph pre-reduction + few atomics into out =====
// Gather inner loop: LDS edge staging + broadcast reads (as in D23).
__global__ __launch_bounds__(1024) void d5_kernel(const int* __restrict__ batch,
        float* __restrict__ ws, float* __restrict__ out) {
    __shared__ float vec[16][88];
    __shared__ int   bix[16];
    __shared__ int2  Ed[16][64];       // 8 KB per-wave edge stage

    const unsigned long long* pck = (const unsigned long long*)(ws + OFF_PCK);
    const int2*  epair = (const int2*)(ws + OFF_EPAIR);
    const float* normv = ws + OFF_NORMV;   // norms (written by D23)
    const float* invcnt= ws + OFF_INV;
    const float* h2pre = ws + OFF_H2;

    const int tid = threadIdx.x;
    const int lane = tid & 63, wv = tid >> 6;        // wv in [0,16)
    const int node = blockIdx.x * 16 + wv;
    const bool hi2 = lane < (OUTF - 64);
    const int b = batch[node];
    const float inv = invcnt[b];
    const unsigned long long pkn = pck[(size_t)node * PCKS];
    const float di2 = 1.0f / (pk_deg(pkn) + 1.0f);
    const float* Hn = h2pre + (size_t)node * OUTF;
    float a0 = di2 * Hn[lane],                  a1 = 0.f, a2 = 0.f, a3 = 0.f;
    float c0 = hi2 ? di2 * Hn[64 + lane] : 0.f, c1 = 0.f, c2 = 0.f, c3 = 0.f;
    const int cnt = min((int)(pkn >> 40), CAP);
    const int2* pe = epair + (size_t)node * CAP;

    for (int base = 0; base < cnt; base += 64) {
        int rem = cnt - base;
        int   sl = 0;
        float nl = 0.f;
        if (lane < rem) {
            sl = pe[base + lane].x;
            nl = normv[(size_t)node * CAP + base + lane];
        }
        Ed[wv][lane] = make_int2(sl, __float_as_int(nl));
        int m = rem < 64 ? rem : 64;
        int j = 0;
        for (; j + 8 <= m; j += 8) {               // 8 rows (16 loads) in flight
            int2 e0 = Ed[wv][j],     e1 = Ed[wv][j + 1];
            int2 e2 = Ed[wv][j + 2], e3 = Ed[wv][j + 3];
            int2 e4 = Ed[wv][j + 4], e5 = Ed[wv][j + 5];
            int2 e6 = Ed[wv][j + 6], e7 = Ed[wv][j + 7];
            const float* H0 = h2pre + (size_t)e0.x * OUTF;
            const float* H1 = h2pre + (size_t)e1.x * OUTF;
            const float* H2 = h2pre + (size_t)e2.x * OUTF;
            const float* H3 = h2pre + (size_t)e3.x * OUTF;
            const float* H4 = h2pre + (size_t)e4.x * OUTF;
            const float* H5 = h2pre + (size_t)e5.x * OUTF;
            const float* H6 = h2pre + (size_t)e6.x * OUTF;
            const float* H7 = h2pre + (size_t)e7.x * OUTF;
            float n0 = __int_as_float(e0.y), n1 = __int_as_float(e1.y);
            float n2 = __int_as_float(e2.y), n3 = __int_as_float(e3.y);
            float n4 = __int_as_float(e4.y), n5 = __int_as_float(e5.y);
            float n6 = __int_as_float(e6.y), n7 = __int_as_float(e7.y);
            float v0 = H0[lane], v1 = H1[lane], v2 = H2[lane], v3 = H3[lane];
            float v4 = H4[lane], v5 = H5[lane], v6 = H6[lane], v7 = H7[lane];
            a0 += n0 * v0; a1 += n1 * v1; a2 += n2 * v2; a3 += n3 * v3;
            a0 += n4 * v4; a1 += n5 * v5; a2 += n6 * v6; a3 += n7 * v7;
            if (hi2) {
                float w0 = H0[64 + lane], w1 = H1[64 + lane];
                float w2 = H2[64 + lane], w3 = H3[64 + lane];
                float w4 = H4[64 + lane], w5 = H5[64 + lane];
                float w6 = H6[64 + lane], w7 = H7[64 + lane];
                c0 += n0 * w0; c1 += n1 * w1; c2 += n2 * w2; c3 += n3 * w3;
                c0 += n4 * w4; c1 += n5 * w5; c2 += n6 * w6; c3 += n7 * w7;
            }
        }
        for (; j < m; ++j) {
            int2 e0 = Ed[wv][j];
            const float* H0 = h2pre + (size_t)e0.x * OUTF;
            float n0 = __int_as_float(e0.y);
            a0 += n0 * H0[lane];
            if (hi2) c0 += n0 * H0[64 + lane];
        }
    }
    vec[wv][lane] = ((a0 + a1) + (a2 + a3)) * inv;
    if (hi2) vec[wv][64 + lane] = ((c0 + c1) + (c2 + c3)) * inv;
    if (lane == 0) bix[wv] = b;
    __syncthreads();
    // per-graph pre-reduction over the 16 sorted nodes: 1 atomic per (graph, feat) per block
    if (tid < OUTF) {
        int curb = bix[0];
        float acc = 0.f;
#pragma unroll
        for (int w = 0; w < 16; ++w) {
            int bw = bix[w];
            if (bw != curb) {
                atomicAdd(&out[curb * OUTF + tid], acc);
                curb = bw; acc = 0.f;
            }
            acc += vec[w][tid];
        }
        atomicAdd(&out[curb * OUTF + tid], acc);
    }
}

extern "C" void kernel_launch(void* const* d_in, const int* in_sizes, int n_in,
                              void* d_out, int out_size, void* d_ws, size_t ws_size,
                              hipStream_t stream) {
    const float* x     = (const float*)d_in[0];
    const int*   ei    = (const int*)  d_in[1];
    const float* ea    = (const float*)d_in[2];
    const int*   batch = (const int*)  d_in[3];
    const float* W1    = (const float*)d_in[4];
    const float* b1    = (const float*)d_in[5];
    const float* Win   = (const float*)d_in[6];
    const float* b_in  = (const float*)d_in[7];
    const float* Wout  = (const float*)d_in[8];
    const float* b_out = (const float*)d_in[9];
    const float* W2    = (const float*)d_in[10];
    const float* b2    = (const float*)d_in[11];
    float* out = (float*)d_out;
    float* ws  = (float*)d_ws;

    // zero padded pck array (N lines of 64 B)
    (void)hipMemsetAsync(ws + OFF_PCK, 0, (size_t)N * 64, stream);
    d1_kernel<<<513, 256, 0, stream>>>(x, W1, ei, ea, batch, b2, ws, out);
    d23_kernel<<<N / 16, 1024, 0, stream>>>(Win, b1, b_in, ws);
    attn_kernel<<<dim3(N / 256, HEADS, NSPLIT), 1024, 0, stream>>>(ws, ws);
    d4b_kernel<<<N / 16, 256, 0, stream>>>(Wout, b_out, W2, ws);
    d5_kernel<<<N / 16, 1024, 0, stream>>>(batch, ws, out);
}